// Round 1
// baseline (1619.144 us; speedup 1.0000x reference)
//
#include <hip/hip_runtime.h>
#include <hip/hip_bf16.h>
#include <stdint.h>

typedef __attribute__((ext_vector_type(8))) short bf16x8;
typedef __attribute__((ext_vector_type(4))) float f32x4;
typedef __attribute__((ext_vector_type(4))) int int4v;

#define DEVI static __device__ __forceinline__

DEVI unsigned short f2b(float f) {
  union { float f; unsigned u; } v; v.f = f;
  unsigned r = (v.u + 0x7FFFu + ((v.u >> 16) & 1u)) >> 16;
  return (unsigned short)r;
}
DEVI float b2f(unsigned short h) {
  union { unsigned u; float f; } v; v.u = ((unsigned)h) << 16;
  return v.f;
}
DEVI unsigned encf(float f) {
  union { float f; unsigned u; } v; v.f = f;
  return (v.u & 0x80000000u) ? ~v.u : (v.u | 0x80000000u);
}
DEVI float decf(unsigned u) {
  union { unsigned u; float f; } v;
  v.u = (u & 0x80000000u) ? (u & 0x7FFFFFFFu) : ~u;
  return v.f;
}
DEVI void gload16(const void* g, void* l) {
  __builtin_amdgcn_global_load_lds(
      (const __attribute__((address_space(1))) unsigned int*)g,
      (__attribute__((address_space(3))) unsigned int*)l, 16, 0, 0);
}

// ---------------- weight reorder: dst[r][tap][ci] bf16 <- src[r][ci][tap] f32
__global__ void k_reorder_w(const float* __restrict__ src, unsigned short* __restrict__ dst,
                            int lgCI, long total) {
  int CI = 1 << lgCI;
  for (long idx = (long)blockIdx.x * 256 + threadIdx.x; idx < total;
       idx += (long)gridDim.x * 256) {
    int ci = (int)(idx & (CI - 1));
    int rt = (int)(idx >> lgCI);
    int tap = rt % 9;
    int r = rt / 9;
    dst[idx] = f2b(src[((size_t)r * CI + ci) * 9 + tap]);
  }
}

// WgT[p][o][tap][ci] f32 <- Wg[p][o][ci][tap]
__global__ void k_reorder_wg(const float* __restrict__ src, float* __restrict__ dst) {
  int idx = blockIdx.x * 256 + threadIdx.x;  // total 73728
  int ci = idx & 1023;
  int rt = idx >> 10;
  int tap = rt % 9;
  int po = rt / 9;  // p*2+o
  dst[idx] = src[((size_t)po * 1024 + ci) * 9 + tap];
}

// ---------------- centerpad: x[2] NCHW f32 -> [2][66][66][512] bf16 (interior)
__global__ __launch_bounds__(256) void k_centerpad(const float* __restrict__ xin,
                                                   unsigned short* __restrict__ cp) {
  __shared__ unsigned short lds[64 * 66];
  int t = threadIdx.x;
  int y = blockIdx.x;  // 0..63
  int b = blockIdx.y;  // 0..1
  const float* src = xin + ((size_t)(2 * 2 + b) * 512) * 4096 + y * 64;
  for (int c0 = 0; c0 < 512; c0 += 64) {
#pragma unroll
    for (int r = 0; r < 16; ++r) {
      int ci = r * 4 + (t >> 6);
      int xx = t & 63;
      lds[ci * 66 + xx] = f2b(src[(size_t)(c0 + ci) * 4096 + xx]);
    }
    __syncthreads();
    int xp = t >> 2;
    int cc = (t & 3) * 16;
    __align__(16) unsigned short vals[16];
#pragma unroll
    for (int i = 0; i < 16; i++) vals[i] = lds[(cc + i) * 66 + xp];
    unsigned short* dst = cp + ((size_t)(b * 66 + y + 1) * 66 + (xp + 1)) * 512 + c0 + cc;
    *(int4v*)(dst) = *(const int4v*)(vals);
    *(int4v*)(dst + 8) = *(const int4v*)(vals + 8);
    __syncthreads();
  }
}

// ---------------- correlation partials: corrpart[part][pair][b][25][64][64]
__global__ __launch_bounds__(256) void k_corr(const float* __restrict__ xin,
                                              float* __restrict__ corrpart) {
  __shared__ float f1h[2][20][21];
  int t = threadIdx.x;
  int tx = t & 15, ty = t >> 4;
  int x0 = blockIdx.x * 16, y0 = blockIdx.y * 16;
  int z = blockIdx.z;
  int b = z & 1, pair = (z >> 1) & 3, part = z >> 3;
  int s = pair < 2 ? pair : pair + 1;
  const float* f2 = xin + ((size_t)(2 * 2 + b) * 512) * 4096;
  const float* f1 = xin + ((size_t)(s * 2 + b) * 512) * 4096;
  float acc[25];
#pragma unroll
  for (int d = 0; d < 25; d++) acc[d] = 0.f;
  int y = y0 + ty, x = x0 + tx;
  for (int c = part * 128; c < part * 128 + 128; c += 2) {
    for (int k = t; k < 800; k += 256) {
      int ch = k / 400, e = k - ch * 400;
      int r = e / 20, ccx = e - r * 20;
      int gy = y0 + r - 2, gx = x0 + ccx - 2;
      float v = 0.f;
      if ((unsigned)gy < 64u && (unsigned)gx < 64u)
        v = f1[(size_t)(c + ch) * 4096 + gy * 64 + gx];
      f1h[ch][r][ccx] = v;
    }
    float f2a = f2[(size_t)c * 4096 + y * 64 + x];
    float f2c = f2[(size_t)(c + 1) * 4096 + y * 64 + x];
    __syncthreads();
#pragma unroll
    for (int d = 0; d < 25; ++d) {
      int di = d / 5, dj = d % 5;
      acc[d] += f2a * f1h[0][ty + di][tx + dj] + f2c * f1h[1][ty + di][tx + dj];
    }
    __syncthreads();
  }
  float* out = corrpart + ((size_t)((part * 4 + pair) * 2 + b) * 25) * 4096;
#pragma unroll
  for (int d = 0; d < 25; d++) out[(size_t)d * 4096 + y * 64 + x] = acc[d];
}

// ---------------- combine partials + global max per pair
__global__ __launch_bounds__(256) void k_corr_combine(const float* __restrict__ cpart,
                                                      float* __restrict__ corr,
                                                      unsigned* __restrict__ maxb) {
  const size_t PERPAIR = (size_t)2 * 25 * 4096;  // 204800
  int pair = blockIdx.y;
  size_t i4 = ((size_t)blockIdx.x * 256 + threadIdx.x) * 4;
  f32x4 sacc = {0.f, 0.f, 0.f, 0.f};
#pragma unroll
  for (int p = 0; p < 4; p++)
    sacc += *(const f32x4*)(cpart + ((size_t)(p * 4 + pair)) * PERPAIR + i4);
  *(f32x4*)(corr + (size_t)pair * PERPAIR + i4) = sacc;
  float m = fmaxf(fmaxf(sacc[0], sacc[1]), fmaxf(sacc[2], sacc[3]));
#pragma unroll
  for (int off = 32; off; off >>= 1) m = fmaxf(m, __shfl_xor(m, off));
  __shared__ float wm[4];
  if ((threadIdx.x & 63) == 0) wm[threadIdx.x >> 6] = m;
  __syncthreads();
  if (threadIdx.x == 0) {
    float mm = fmaxf(fmaxf(wm[0], wm[1]), fmaxf(wm[2], wm[3]));
    atomicMax(maxb + pair, encf(mm));
  }
}

// ---------------- softmax + 5x5 gather -> nfpad [pair][b][66][66][512] bf16
__global__ __launch_bounds__(256) void k_attn_nf(const float* __restrict__ xin,
                                                 const float* __restrict__ corr,
                                                 const unsigned* __restrict__ maxb,
                                                 unsigned short* __restrict__ nfpad) {
  __shared__ float f1h[2][20][21];
  __shared__ unsigned short ob[32][256];
  int t = threadIdx.x;
  int tx = t & 15, ty = t >> 4;
  int x0 = blockIdx.x * 16, y0 = blockIdx.y * 16;
  int z = blockIdx.z;
  int b = z & 1, pair = (z >> 1) & 3, cg = z >> 3;
  int s = pair < 2 ? pair : pair + 1;
  const float* f1 = xin + ((size_t)(s * 2 + b) * 512) * 4096;
  int y = y0 + ty, x = x0 + tx;
  const float* cr = corr + ((size_t)(pair * 2 + b)) * 25 * 4096 + y * 64 + x;
  float p[25];
  float mx = -1e30f;
#pragma unroll
  for (int d = 0; d < 25; d++) {
    p[d] = cr[(size_t)d * 4096];
    mx = fmaxf(mx, p[d]);
  }
  float gscale = 20.f / decf(maxb[pair]);
  float ssum = 0.f;
#pragma unroll
  for (int d = 0; d < 25; d++) {
    p[d] = __expf((p[d] - mx) * gscale);
    ssum += p[d];
  }
  float inv = 1.f / ssum;
#pragma unroll
  for (int d = 0; d < 25; d++) p[d] *= inv;

  for (int cb = 0; cb < 4; ++cb) {
    int cbase = cg * 128 + cb * 32;
    for (int cc = 0; cc < 32; cc += 2) {
      int c = cbase + cc;
      for (int k = t; k < 800; k += 256) {
        int ch = k / 400, e = k - ch * 400;
        int r = e / 20, ccx = e - r * 20;
        int gy = y0 + r - 2, gx = x0 + ccx - 2;
        float v = 0.f;
        if ((unsigned)gy < 64u && (unsigned)gx < 64u)
          v = f1[(size_t)(c + ch) * 4096 + gy * 64 + gx];
        f1h[ch][r][ccx] = v;
      }
      __syncthreads();
#pragma unroll
      for (int ch = 0; ch < 2; ++ch) {
        float nf = 0.f;
#pragma unroll
        for (int d = 0; d < 25; d++) nf += p[d] * f1h[ch][ty + d / 5][tx + d % 5];
        ob[cc + ch][t] = f2b(nf);
      }
      __syncthreads();
    }
    unsigned short* dst =
        nfpad + (((size_t)(pair * 2 + b) * 66 + (y + 1)) * 66 + (x + 1)) * 512 + cbase;
    __align__(16) unsigned short vals[32];
#pragma unroll
    for (int i = 0; i < 32; i++) vals[i] = ob[i][t];
#pragma unroll
    for (int q = 0; q < 4; q++) *(int4v*)(dst + q * 8) = *(const int4v*)(vals + q * 8);
    __syncthreads();
  }
}

// ---------------- gate conv (f32): gw[pair][b][o][64][64]
__global__ __launch_bounds__(256) void k_gate(const unsigned short* __restrict__ cp,
                                              const unsigned short* __restrict__ nfp,
                                              const float* __restrict__ wgt,
                                              const float* __restrict__ bg,
                                              float* __restrict__ gw) {
  int t = threadIdx.x;
  int xt = blockIdx.x;  // 0..3
  int y = blockIdx.y;   // 0..63
  int z = blockIdx.z;   // b + 2*pair
  int b = z & 1, pair = z >> 1;
  int x = xt * 16 + (t >> 4);
  int cil = t & 15;
  int cig = cil * 64;
  int half = cig >> 9;
  int ch0 = cig & 511;
  const unsigned short* src = half ? (nfp + ((size_t)(pair * 2 + b)) * 66 * 66 * 512)
                                   : (cp + ((size_t)b) * 66 * 66 * 512);
  const float* w = wgt + (size_t)pair * 2 * 9 * 1024;
  float a0 = 0.f, a1 = 0.f;
  for (int tap = 0; tap < 9; ++tap) {
    int ky = tap / 3, kx = tap % 3;
    const unsigned short* ip = src + ((size_t)(y + ky) * 66 + (x + kx)) * 512 + ch0;
    const float* w0 = w + ((size_t)0 * 9 + tap) * 1024 + cig;
    const float* w1 = w + ((size_t)1 * 9 + tap) * 1024 + cig;
#pragma unroll
    for (int q = 0; q < 8; ++q) {
      bf16x8 v8 = *(const bf16x8*)(ip + q * 8);
      f32x4 wa0 = *(const f32x4*)(w0 + q * 8);
      f32x4 wb0 = *(const f32x4*)(w0 + q * 8 + 4);
      f32x4 wa1 = *(const f32x4*)(w1 + q * 8);
      f32x4 wb1 = *(const f32x4*)(w1 + q * 8 + 4);
#pragma unroll
      for (int e = 0; e < 4; e++) {
        float f0 = b2f((unsigned short)v8[e]);
        float f1v = b2f((unsigned short)v8[e + 4]);
        a0 += f0 * wa0[e] + f1v * wb0[e];
        a1 += f0 * wa1[e] + f1v * wb1[e];
      }
    }
  }
#pragma unroll
  for (int md = 8; md; md >>= 1) {
    a0 += __shfl_xor(a0, md);
    a1 += __shfl_xor(a1, md);
  }
  if (cil == 0) {
    float g0 = 1.f / (1.f + __expf(-(a0 + bg[pair * 2 + 0])));
    float g1 = 1.f / (1.f + __expf(-(a1 + bg[pair * 2 + 1])));
    gw[(((size_t)(pair * 2 + b) * 2 + 0) * 64 + y) * 64 + x] = g0;
    gw[(((size_t)(pair * 2 + b) * 2 + 1) * 64 + y) * 64 + x] = g1;
  }
}

// ---------------- fg = [center*g0, nf*g1] -> fgpad [2][66][66][1024] bf16
__global__ __launch_bounds__(256) void k_fg(const unsigned short* __restrict__ cp,
                                            const unsigned short* __restrict__ nfp,
                                            const float* __restrict__ gw,
                                            unsigned short* __restrict__ fgp, int pair) {
  size_t idx = (size_t)blockIdx.x * 256 + threadIdx.x;  // 2*4096*128
  int chunk = (int)(idx & 127);
  size_t px = idx >> 7;
  int b = (int)(px >> 12), rem = (int)(px & 4095);
  int y = rem >> 6, x = rem & 63;
  int ci0 = chunk * 8;
  int half = ci0 >> 9;
  float g = gw[(((size_t)(pair * 2 + b) * 2 + half) * 64 + y) * 64 + x];
  const unsigned short* src = half ? (nfp + ((size_t)(pair * 2 + b)) * 66 * 66 * 512)
                                   : (cp + (size_t)b * 66 * 66 * 512);
  size_t poff = ((size_t)(y + 1) * 66 + (x + 1)) * 512 + (ci0 - half * 512);
  bf16x8 v = *(const bf16x8*)(src + poff);
  __align__(16) unsigned short o[8];
#pragma unroll
  for (int e = 0; e < 8; e++) o[e] = f2b(b2f((unsigned short)v[e]) * g);
  *(int4v*)(fgp + ((size_t)(b * 66 + y + 1) * 66 + (x + 1)) * 1024 + ci0) = *(const int4v*)o;
}

// ---------------- implicit-GEMM conv: M=512(co) x N=8192(px), K=9*CI, bf16 MFMA
// BM=64, BN=128, BK=64; 512 blocks x 256 thr (4 waves 2x2, wave tile 32x64)
template <int CI, int MODE>
__global__ __launch_bounds__(256) void conv_gemm(const unsigned short* __restrict__ inPad,
                                                 const unsigned short* __restrict__ WT,
                                                 const float* __restrict__ bias,
                                                 unsigned short* __restrict__ outB,
                                                 float* __restrict__ outF, int coBase) {
  constexpr int K = 9 * CI;
  constexpr int KT = K / 64;
  __shared__ unsigned short As[64 * 64];
  __shared__ unsigned short Bs[128 * 64];

  int t = threadIdx.x;
  int bid = blockIdx.x;
  int swz = (bid & 7) * 64 + (bid >> 3);  // XCD swizzle (512 % 8 == 0)
  int m = swz & 7, n = swz >> 3;
  int co0 = m * 64, n0 = n * 128;

  int rowA[2], cA[2];
  const unsigned short* gA[2];
#pragma unroll
  for (int r = 0; r < 2; r++) {
    int idx = r * 256 + t;
    rowA[r] = idx >> 3;
    cA[r] = (idx & 7) ^ (rowA[r] & 7);
    gA[r] = WT + (size_t)(co0 + rowA[r]) * K + cA[r] * 8;
  }
  int pixrow[4], pixcol[4], cB[4];
#pragma unroll
  for (int r = 0; r < 4; r++) {
    int idx = r * 256 + t;
    int rowB = idx >> 3;
    cB[r] = (idx & 7) ^ (rowB & 7);
    int ng = n0 + rowB;
    int bb = ng >> 12, yy = (ng >> 6) & 63, xx = ng & 63;
    pixrow[r] = bb * 66 + yy;
    pixcol[r] = xx;
  }

  f32x4 acc[2][4];
#pragma unroll
  for (int i = 0; i < 2; i++)
#pragma unroll
    for (int j = 0; j < 4; j++) acc[i][j] = f32x4{0.f, 0.f, 0.f, 0.f};

  int wid = t >> 6, l = t & 63;
  int wm = wid >> 1, wn = wid & 1;
  int lrow = l & 15, lk = l >> 4, ls = l & 7;

  for (int kt = 0; kt < KT; ++kt) {
    if (kt) __syncthreads();
    int kb = kt * 64;
#pragma unroll
    for (int r = 0; r < 2; r++)
      gload16(gA[r] + kb, As + (size_t)(r * 256 + t) * 8);
    int tap, kci;
    if (CI == 1024) { tap = kt >> 4; kci = (kt & 15) * 64; }
    else { tap = kt >> 5; kci = (kt & 31) * 64; }
    int ky = tap / 3, kx = tap - ky * 3;
#pragma unroll
    for (int r = 0; r < 4; r++) {
      const unsigned short* g =
          inPad + ((size_t)(pixrow[r] + ky) * 66 + (pixcol[r] + kx)) * CI + kci + cB[r] * 8;
      gload16(g, Bs + (size_t)(r * 256 + t) * 8);
    }
    __syncthreads();
#pragma unroll
    for (int kk = 0; kk < 2; ++kk) {
      int csw = ((kk * 4 + lk) ^ ls) * 8;
      bf16x8 a[2], b[4];
#pragma unroll
      for (int i = 0; i < 2; i++)
        a[i] = *(const bf16x8*)(As + (wm * 32 + i * 16 + lrow) * 64 + csw);
#pragma unroll
      for (int j = 0; j < 4; j++)
        b[j] = *(const bf16x8*)(Bs + (wn * 64 + j * 16 + lrow) * 64 + csw);
#pragma unroll
      for (int i = 0; i < 2; i++)
#pragma unroll
        for (int j = 0; j < 4; j++)
          acc[i][j] = __builtin_amdgcn_mfma_f32_16x16x32_bf16(a[i], b[j], acc[i][j], 0, 0, 0);
    }
  }

#pragma unroll
  for (int i = 0; i < 2; i++) {
#pragma unroll
    for (int j = 0; j < 4; j++) {
      int col = wn * 64 + j * 16 + lrow;
      int ng = n0 + col;
      int bb = ng >> 12, yy = (ng >> 6) & 63, xx = ng & 63;
#pragma unroll
      for (int r = 0; r < 4; r++) {
        int row = wm * 32 + i * 16 + lk * 4 + r;
        int co = co0 + row;
        float v = acc[i][j][r] + bias[co];
        v = v > 0.f ? v : 0.f;
        if (MODE == 0) {
          outB[((size_t)(bb * 66 + yy + 1) * 66 + (xx + 1)) * 2048 + coBase + co] = f2b(v);
        } else {
          outF[((size_t)(bb * 512 + co)) * 4096 + yy * 64 + xx] = v;
        }
      }
    }
  }
}

extern "C" void kernel_launch(void* const* d_in, const int* in_sizes, int n_in,
                              void* d_out, int out_size, void* d_ws, size_t ws_size,
                              hipStream_t stream) {
  const float* x = (const float*)d_in[0];
  const float* Wg = (const float*)d_in[1];
  const float* bg = (const float*)d_in[2];
  const float* Wd = (const float*)d_in[3];
  const float* bd = (const float*)d_in[4];
  const float* Wc = (const float*)d_in[5];
  const float* bc = (const float*)d_in[6];
  float* out = (float*)d_out;

  char* ws = (char*)d_ws;
  size_t off = 0;
  auto alloc = [&](size_t bytes) {
    void* p = ws + off;
    off = (off + bytes + 255) & ~(size_t)255;
    return p;
  };
  const size_t SZ_WDT = (size_t)2048 * 9216 * 2;
  const size_t SZ_WCT = (size_t)512 * 18432 * 2;
  const size_t SZ_WGT = (size_t)4 * 2 * 9 * 1024 * 4;
  const size_t SZ_CP = (size_t)2 * 66 * 66 * 512 * 2;
  const size_t SZ_NF = (size_t)4 * 2 * 66 * 66 * 512 * 2;
  const size_t SZ_FG = (size_t)2 * 66 * 66 * 1024 * 2;
  const size_t SZ_GT = (size_t)2 * 66 * 66 * 2048 * 2;
  const size_t SZ_CORR = (size_t)4 * 2 * 25 * 4096 * 4;
  const size_t SZ_CPART = SZ_CORR * 4;
  const size_t SZ_GW = (size_t)4 * 2 * 2 * 4096 * 4;

  unsigned short* WdT = (unsigned short*)alloc(SZ_WDT);
  unsigned short* WcT = (unsigned short*)alloc(SZ_WCT);
  float* WgT = (float*)alloc(SZ_WGT);
  unsigned short* centerpad = (unsigned short*)alloc(SZ_CP);
  unsigned short* nfpad = (unsigned short*)alloc(SZ_NF);
  unsigned short* fgpad = (unsigned short*)alloc(SZ_FG);
  unsigned short* gatedpad = (unsigned short*)alloc(SZ_GT);
  float* corr = (float*)alloc(SZ_CORR);
  float* cpart = (float*)alloc(SZ_CPART);
  float* gw = (float*)alloc(SZ_GW);
  unsigned* maxb = (unsigned*)alloc(256);

  hipMemsetAsync(centerpad, 0, SZ_CP, stream);
  hipMemsetAsync(nfpad, 0, SZ_NF, stream);
  hipMemsetAsync(fgpad, 0, SZ_FG, stream);
  hipMemsetAsync(gatedpad, 0, SZ_GT, stream);
  hipMemsetAsync(maxb, 0, 64, stream);

  k_reorder_w<<<4096, 256, 0, stream>>>(Wd, WdT, 10, (long)2048 * 9216);
  k_reorder_w<<<4096, 256, 0, stream>>>(Wc, WcT, 11, (long)512 * 18432);
  k_reorder_wg<<<288, 256, 0, stream>>>(Wg, WgT);
  k_centerpad<<<dim3(64, 2), 256, 0, stream>>>(x, centerpad);
  k_corr<<<dim3(4, 4, 32), 256, 0, stream>>>(x, cpart);
  k_corr_combine<<<dim3(200, 4), 256, 0, stream>>>(cpart, corr, maxb);
  k_attn_nf<<<dim3(4, 4, 32), 256, 0, stream>>>(x, corr, maxb, nfpad);
  k_gate<<<dim3(4, 64, 8), 256, 0, stream>>>(centerpad, nfpad, WgT, bg, gw);

  for (int pair = 0; pair < 4; ++pair) {
    k_fg<<<4096, 256, 0, stream>>>(centerpad, nfpad, gw, fgpad, pair);
    conv_gemm<1024, 0><<<512, 256, 0, stream>>>(
        fgpad, WdT + (size_t)pair * 512 * 9216, bd + pair * 512, gatedpad, nullptr,
        pair * 512);
  }
  conv_gemm<2048, 1><<<512, 256, 0, stream>>>(gatedpad, WcT, bc, nullptr, out, 0);
}

// Round 2
// 1277.573 us; speedup vs baseline: 1.2674x; 1.2674x over previous
//
#include <hip/hip_runtime.h>
#include <hip/hip_bf16.h>
#include <stdint.h>

typedef __attribute__((ext_vector_type(8))) short bf16x8;
typedef __attribute__((ext_vector_type(4))) float f32x4;
typedef __attribute__((ext_vector_type(4))) int int4v;

#define DEVI static __device__ __forceinline__

DEVI unsigned short f2b(float f) {
  union { float f; unsigned u; } v; v.f = f;
  unsigned r = (v.u + 0x7FFFu + ((v.u >> 16) & 1u)) >> 16;
  return (unsigned short)r;
}
DEVI float b2f(unsigned short h) {
  union { unsigned u; float f; } v; v.u = ((unsigned)h) << 16;
  return v.f;
}
DEVI unsigned encf(float f) {
  union { float f; unsigned u; } v; v.f = f;
  return (v.u & 0x80000000u) ? ~v.u : (v.u | 0x80000000u);
}
DEVI float decf(unsigned u) {
  union { unsigned u; float f; } v;
  v.u = (u & 0x80000000u) ? (u & 0x7FFFFFFFu) : ~u;
  return v.f;
}
DEVI void gload16(const void* g, void* l) {
  __builtin_amdgcn_global_load_lds(
      (const __attribute__((address_space(1))) unsigned int*)g,
      (__attribute__((address_space(3))) unsigned int*)l, 16, 0, 0);
}

// ---------------- weight reorder: dst[r][tap][ci] bf16 <- src[r][ci][tap] f32
__global__ void k_reorder_w(const float* __restrict__ src, unsigned short* __restrict__ dst,
                            int lgCI, long total) {
  int CI = 1 << lgCI;
  for (long idx = (long)blockIdx.x * 256 + threadIdx.x; idx < total;
       idx += (long)gridDim.x * 256) {
    int ci = (int)(idx & (CI - 1));
    int rt = (int)(idx >> lgCI);
    int tap = rt % 9;
    int r = rt / 9;
    dst[idx] = f2b(src[((size_t)r * CI + ci) * 9 + tap]);
  }
}

// WgT[p][o][tap][ci] f32 <- Wg[p][o][ci][tap]
__global__ void k_reorder_wg(const float* __restrict__ src, float* __restrict__ dst) {
  int idx = blockIdx.x * 256 + threadIdx.x;  // total 73728
  int ci = idx & 1023;
  int rt = idx >> 10;
  int tap = rt % 9;
  int po = rt / 9;  // p*2+o
  dst[idx] = src[((size_t)po * 1024 + ci) * 9 + tap];
}

// ---------------- centerpad: x[2] NCHW f32 -> [2][66][66][512] bf16 (interior)
__global__ __launch_bounds__(256) void k_centerpad(const float* __restrict__ xin,
                                                   unsigned short* __restrict__ cp) {
  __shared__ unsigned short lds[64 * 66];
  int t = threadIdx.x;
  int y = blockIdx.x;  // 0..63
  int b = blockIdx.y;  // 0..1
  const float* src = xin + ((size_t)(2 * 2 + b) * 512) * 4096 + y * 64;
  for (int c0 = 0; c0 < 512; c0 += 64) {
#pragma unroll
    for (int r = 0; r < 16; ++r) {
      int ci = r * 4 + (t >> 6);
      int xx = t & 63;
      lds[ci * 66 + xx] = f2b(src[(size_t)(c0 + ci) * 4096 + xx]);
    }
    __syncthreads();
    int xp = t >> 2;
    int cc = (t & 3) * 16;
    __align__(16) unsigned short vals[16];
#pragma unroll
    for (int i = 0; i < 16; i++) vals[i] = lds[(cc + i) * 66 + xp];
    unsigned short* dst = cp + ((size_t)(b * 66 + y + 1) * 66 + (xp + 1)) * 512 + c0 + cc;
    *(int4v*)(dst) = *(const int4v*)(vals);
    *(int4v*)(dst + 8) = *(const int4v*)(vals + 8);
    __syncthreads();
  }
}

// ---------------- correlation partials: corrpart[part][pair][b][25][64][64]
__global__ __launch_bounds__(256) void k_corr(const float* __restrict__ xin,
                                              float* __restrict__ corrpart) {
  __shared__ float f1h[2][20][21];
  int t = threadIdx.x;
  int tx = t & 15, ty = t >> 4;
  int x0 = blockIdx.x * 16, y0 = blockIdx.y * 16;
  int z = blockIdx.z;
  int b = z & 1, pair = (z >> 1) & 3, part = z >> 3;
  int s = pair < 2 ? pair : pair + 1;
  const float* f2 = xin + ((size_t)(2 * 2 + b) * 512) * 4096;
  const float* f1 = xin + ((size_t)(s * 2 + b) * 512) * 4096;
  float acc[25];
#pragma unroll
  for (int d = 0; d < 25; d++) acc[d] = 0.f;
  int y = y0 + ty, x = x0 + tx;
  for (int c = part * 128; c < part * 128 + 128; c += 2) {
    for (int k = t; k < 800; k += 256) {
      int ch = k / 400, e = k - ch * 400;
      int r = e / 20, ccx = e - r * 20;
      int gy = y0 + r - 2, gx = x0 + ccx - 2;
      float v = 0.f;
      if ((unsigned)gy < 64u && (unsigned)gx < 64u)
        v = f1[(size_t)(c + ch) * 4096 + gy * 64 + gx];
      f1h[ch][r][ccx] = v;
    }
    float f2a = f2[(size_t)c * 4096 + y * 64 + x];
    float f2c = f2[(size_t)(c + 1) * 4096 + y * 64 + x];
    __syncthreads();
#pragma unroll
    for (int d = 0; d < 25; ++d) {
      int di = d / 5, dj = d % 5;
      acc[d] += f2a * f1h[0][ty + di][tx + dj] + f2c * f1h[1][ty + di][tx + dj];
    }
    __syncthreads();
  }
  float* out = corrpart + ((size_t)((part * 4 + pair) * 2 + b) * 25) * 4096;
#pragma unroll
  for (int d = 0; d < 25; d++) out[(size_t)d * 4096 + y * 64 + x] = acc[d];
}

// ---------------- combine partials + global max per pair
__global__ __launch_bounds__(256) void k_corr_combine(const float* __restrict__ cpart,
                                                      float* __restrict__ corr,
                                                      unsigned* __restrict__ maxb) {
  const size_t PERPAIR = (size_t)2 * 25 * 4096;  // 204800
  int pair = blockIdx.y;
  size_t i4 = ((size_t)blockIdx.x * 256 + threadIdx.x) * 4;
  f32x4 sacc = {0.f, 0.f, 0.f, 0.f};
#pragma unroll
  for (int p = 0; p < 4; p++)
    sacc += *(const f32x4*)(cpart + ((size_t)(p * 4 + pair)) * PERPAIR + i4);
  *(f32x4*)(corr + (size_t)pair * PERPAIR + i4) = sacc;
  float m = fmaxf(fmaxf(sacc[0], sacc[1]), fmaxf(sacc[2], sacc[3]));
#pragma unroll
  for (int off = 32; off; off >>= 1) m = fmaxf(m, __shfl_xor(m, off));
  __shared__ float wm[4];
  if ((threadIdx.x & 63) == 0) wm[threadIdx.x >> 6] = m;
  __syncthreads();
  if (threadIdx.x == 0) {
    float mm = fmaxf(fmaxf(wm[0], wm[1]), fmaxf(wm[2], wm[3]));
    atomicMax(maxb + pair, encf(mm));
  }
}

// ---------------- softmax + 5x5 gather -> nfpad [pair][b][66][66][512] bf16
__global__ __launch_bounds__(256) void k_attn_nf(const float* __restrict__ xin,
                                                 const float* __restrict__ corr,
                                                 const unsigned* __restrict__ maxb,
                                                 unsigned short* __restrict__ nfpad) {
  __shared__ float f1h[2][20][21];
  __shared__ unsigned short ob[32][256];
  int t = threadIdx.x;
  int tx = t & 15, ty = t >> 4;
  int x0 = blockIdx.x * 16, y0 = blockIdx.y * 16;
  int z = blockIdx.z;
  int b = z & 1, pair = (z >> 1) & 3, cg = z >> 3;
  int s = pair < 2 ? pair : pair + 1;
  const float* f1 = xin + ((size_t)(s * 2 + b) * 512) * 4096;
  int y = y0 + ty, x = x0 + tx;
  const float* cr = corr + ((size_t)(pair * 2 + b)) * 25 * 4096 + y * 64 + x;
  float p[25];
  float mx = -1e30f;
#pragma unroll
  for (int d = 0; d < 25; d++) {
    p[d] = cr[(size_t)d * 4096];
    mx = fmaxf(mx, p[d]);
  }
  float gscale = 20.f / decf(maxb[pair]);
  float ssum = 0.f;
#pragma unroll
  for (int d = 0; d < 25; d++) {
    p[d] = __expf((p[d] - mx) * gscale);
    ssum += p[d];
  }
  float inv = 1.f / ssum;
#pragma unroll
  for (int d = 0; d < 25; d++) p[d] *= inv;

  for (int cb = 0; cb < 4; ++cb) {
    int cbase = cg * 128 + cb * 32;
    for (int cc = 0; cc < 32; cc += 2) {
      int c = cbase + cc;
      for (int k = t; k < 800; k += 256) {
        int ch = k / 400, e = k - ch * 400;
        int r = e / 20, ccx = e - r * 20;
        int gy = y0 + r - 2, gx = x0 + ccx - 2;
        float v = 0.f;
        if ((unsigned)gy < 64u && (unsigned)gx < 64u)
          v = f1[(size_t)(c + ch) * 4096 + gy * 64 + gx];
        f1h[ch][r][ccx] = v;
      }
      __syncthreads();
#pragma unroll
      for (int ch = 0; ch < 2; ++ch) {
        float nf = 0.f;
#pragma unroll
        for (int d = 0; d < 25; d++) nf += p[d] * f1h[ch][ty + d / 5][tx + d % 5];
        ob[cc + ch][t] = f2b(nf);
      }
      __syncthreads();
    }
    unsigned short* dst =
        nfpad + (((size_t)(pair * 2 + b) * 66 + (y + 1)) * 66 + (x + 1)) * 512 + cbase;
    __align__(16) unsigned short vals[32];
#pragma unroll
    for (int i = 0; i < 32; i++) vals[i] = ob[i][t];
#pragma unroll
    for (int q = 0; q < 4; q++) *(int4v*)(dst + q * 8) = *(const int4v*)(vals + q * 8);
    __syncthreads();
  }
}

// ---------------- gate conv (f32 accum, bf16 acts): coalesced, high-parallelism
// grid (8 xg, 64 y, 8 z=b+2*pair), 256 thr = 8 x-positions x 32 channel-chunks(32ch)
__global__ __launch_bounds__(256) void k_gate2(const unsigned short* __restrict__ cp,
                                               const unsigned short* __restrict__ nfp,
                                               const float* __restrict__ wgt,
                                               const float* __restrict__ bg,
                                               float* __restrict__ gw) {
  int t = threadIdx.x;
  int z = blockIdx.z;
  int b = z & 1, pair = z >> 1;
  int y = blockIdx.y;
  int x = blockIdx.x * 8 + (t >> 5);
  int chunk = t & 31;
  int ci0 = chunk * 32;      // 0..992 over 1024 = [center 512 | nf 512]
  int half = ci0 >> 9;
  int ch0 = ci0 & 511;
  const unsigned short* src = half ? (nfp + ((size_t)(pair * 2 + b)) * 66 * 66 * 512)
                                   : (cp + ((size_t)b) * 66 * 66 * 512);
  const float* w = wgt + (size_t)pair * 2 * 9 * 1024;
  float a0 = 0.f, a1 = 0.f, a0b = 0.f, a1b = 0.f;
  for (int tap = 0; tap < 9; ++tap) {
    int ky = tap / 3, kx = tap % 3;
    const unsigned short* ip = src + ((size_t)(y + ky) * 66 + (x + kx)) * 512 + ch0;
    const float* w0 = w + ((size_t)0 * 9 + tap) * 1024 + ci0;
    const float* w1 = w + ((size_t)1 * 9 + tap) * 1024 + ci0;
#pragma unroll
    for (int q = 0; q < 4; ++q) {
      bf16x8 v8 = *(const bf16x8*)(ip + q * 8);
      f32x4 wa = *(const f32x4*)(w0 + q * 8);
      f32x4 wb = *(const f32x4*)(w0 + q * 8 + 4);
      f32x4 wc = *(const f32x4*)(w1 + q * 8);
      f32x4 wd = *(const f32x4*)(w1 + q * 8 + 4);
#pragma unroll
      for (int e = 0; e < 4; e++) {
        float f0 = b2f((unsigned short)v8[e]);
        float f1v = b2f((unsigned short)v8[e + 4]);
        a0 += f0 * wa[e];
        a0b += f1v * wb[e];
        a1 += f0 * wc[e];
        a1b += f1v * wd[e];
      }
    }
  }
  a0 += a0b;
  a1 += a1b;
#pragma unroll
  for (int md = 1; md < 32; md <<= 1) {
    a0 += __shfl_xor(a0, md);
    a1 += __shfl_xor(a1, md);
  }
  if ((t & 31) == 0) {
    float g0 = 1.f / (1.f + __expf(-(a0 + bg[pair * 2 + 0])));
    float g1 = 1.f / (1.f + __expf(-(a1 + bg[pair * 2 + 1])));
    gw[(((size_t)(pair * 2 + b) * 2 + 0) * 64 + y) * 64 + x] = g0;
    gw[(((size_t)(pair * 2 + b) * 2 + 1) * 64 + y) * 64 + x] = g1;
  }
}

// ---------------- fg = [center*g0, nf*g1] -> fgp[z][2][66][66][1024] bf16
__global__ __launch_bounds__(256) void k_fg(const unsigned short* __restrict__ cp,
                                            const unsigned short* __restrict__ nfp,
                                            const float* __restrict__ gw,
                                            unsigned short* __restrict__ fgp, int pairBase) {
  int pz = blockIdx.y;
  int pair = pairBase + pz;
  unsigned short* dstBase = fgp + (size_t)pz * 2 * 66 * 66 * 1024;
  size_t idx = (size_t)blockIdx.x * 256 + threadIdx.x;  // 2*4096*128
  int chunk = (int)(idx & 127);
  size_t px = idx >> 7;
  int b = (int)(px >> 12), rem = (int)(px & 4095);
  int y = rem >> 6, x = rem & 63;
  int ci0 = chunk * 8;
  int half = ci0 >> 9;
  float g = gw[(((size_t)(pair * 2 + b) * 2 + half) * 64 + y) * 64 + x];
  const unsigned short* src = half ? (nfp + ((size_t)(pair * 2 + b)) * 66 * 66 * 512)
                                   : (cp + (size_t)b * 66 * 66 * 512);
  size_t poff = ((size_t)(y + 1) * 66 + (x + 1)) * 512 + (ci0 - half * 512);
  bf16x8 v = *(const bf16x8*)(src + poff);
  __align__(16) unsigned short o[8];
#pragma unroll
  for (int e = 0; e < 8; e++) o[e] = f2b(b2f((unsigned short)v[e]) * g);
  *(int4v*)(dstBase + ((size_t)(b * 66 + y + 1) * 66 + (x + 1)) * 1024 + ci0) =
      *(const int4v*)o;
}

// ---------------- 128x128x64 implicit-GEMM conv (m97 structure)
// MODE 0: Wd batched over z=pair, bf16 out to gatedpad (+bias+relu)
// MODE 1: Wc direct, f32 NCHW out (+bias+relu)
// MODE 2: Wc split-K over z=half, f32 partials [z][512][8192], no bias
template <int CI, int MODE>
__global__ __launch_bounds__(256) void conv128(const unsigned short* __restrict__ inB,
                                               const unsigned short* __restrict__ WTb,
                                               const float* __restrict__ bias,
                                               unsigned short* __restrict__ outB,
                                               float* __restrict__ outF) {
  constexpr int K = 9 * CI;
  constexpr int KTOT = K / 64;
  constexpr int KT = (MODE == 2) ? KTOT / 2 : KTOT;
  __shared__ unsigned short As[128 * 64];
  __shared__ unsigned short Bs[128 * 64];

  int t = threadIdx.x;
  int z = blockIdx.y;
  const unsigned short* inPad = (MODE == 0) ? inB + (size_t)z * 2 * 66 * 66 * 1024 : inB;
  const unsigned short* WT = (MODE == 0) ? WTb + (size_t)z * 512 * 9216 : WTb;
  int kt0 = (MODE == 2) ? z * KT : 0;

  int bid = blockIdx.x;                       // 256 tiles: 4 M x 64 N
  int swz = (bid & 7) * 32 + (bid >> 3);      // XCD swizzle: each XCD -> contiguous n-range
  int m = swz & 3, n = swz >> 2;
  int co0 = m * 128, n0 = n * 128;

  int rowA[4], cA[4];
  const unsigned short* gA[4];
#pragma unroll
  for (int r = 0; r < 4; r++) {
    int idx = r * 256 + t;
    rowA[r] = idx >> 3;
    cA[r] = (idx & 7) ^ (rowA[r] & 7);
    gA[r] = WT + (size_t)(co0 + rowA[r]) * K + cA[r] * 8;
  }
  int pixrow[4], pixcol[4], cB[4];
#pragma unroll
  for (int r = 0; r < 4; r++) {
    int idx = r * 256 + t;
    int rowB = idx >> 3;
    cB[r] = (idx & 7) ^ (rowB & 7);
    int ng = n0 + rowB;
    int bb = ng >> 12, yy = (ng >> 6) & 63, xx = ng & 63;
    pixrow[r] = bb * 66 + yy;
    pixcol[r] = xx;
  }

  f32x4 acc[4][4];
#pragma unroll
  for (int i = 0; i < 4; i++)
#pragma unroll
    for (int j = 0; j < 4; j++) acc[i][j] = f32x4{0.f, 0.f, 0.f, 0.f};

  int wid = t >> 6, l = t & 63;
  int wm = wid >> 1, wn = wid & 1;
  int lrow = l & 15, lk = l >> 4, ls = l & 7;

  for (int kt = kt0; kt < kt0 + KT; ++kt) {
    if (kt != kt0) __syncthreads();
    int kb = kt * 64;
#pragma unroll
    for (int r = 0; r < 4; r++) gload16(gA[r] + kb, As + (size_t)(r * 256 + t) * 8);
    int tap, kci;
    if (CI == 1024) { tap = kt >> 4; kci = (kt & 15) * 64; }
    else { tap = kt >> 5; kci = (kt & 31) * 64; }
    int ky = tap / 3, kx = tap - ky * 3;
#pragma unroll
    for (int r = 0; r < 4; r++) {
      const unsigned short* g =
          inPad + ((size_t)(pixrow[r] + ky) * 66 + (pixcol[r] + kx)) * CI + kci + cB[r] * 8;
      gload16(g, Bs + (size_t)(r * 256 + t) * 8);
    }
    __syncthreads();
#pragma unroll
    for (int kk = 0; kk < 2; ++kk) {
      int csw = ((kk * 4 + lk) ^ ls) * 8;
      bf16x8 a[4], b[4];
#pragma unroll
      for (int i = 0; i < 4; i++)
        a[i] = *(const bf16x8*)(As + (wm * 64 + i * 16 + lrow) * 64 + csw);
#pragma unroll
      for (int j = 0; j < 4; j++)
        b[j] = *(const bf16x8*)(Bs + (wn * 64 + j * 16 + lrow) * 64 + csw);
#pragma unroll
      for (int i = 0; i < 4; i++)
#pragma unroll
        for (int j = 0; j < 4; j++)
          acc[i][j] = __builtin_amdgcn_mfma_f32_16x16x32_bf16(a[i], b[j], acc[i][j], 0, 0, 0);
    }
  }

#pragma unroll
  for (int i = 0; i < 4; i++) {
#pragma unroll
    for (int j = 0; j < 4; j++) {
      int col = wn * 64 + j * 16 + lrow;
      int ng = n0 + col;
      int bb = ng >> 12, yy = (ng >> 6) & 63, xx = ng & 63;
#pragma unroll
      for (int r = 0; r < 4; r++) {
        int row = wm * 64 + i * 16 + lk * 4 + r;
        int co = co0 + row;
        if (MODE == 0) {
          float v = acc[i][j][r] + bias[z * 512 + co];
          v = v > 0.f ? v : 0.f;
          outB[((size_t)(bb * 66 + yy + 1) * 66 + (xx + 1)) * 2048 + z * 512 + co] = f2b(v);
        } else if (MODE == 1) {
          float v = acc[i][j][r] + bias[co];
          v = v > 0.f ? v : 0.f;
          outF[((size_t)(bb * 512 + co)) * 4096 + yy * 64 + xx] = v;
        } else {
          outF[((size_t)z * 512 + co) * 8192 + ng] = acc[i][j][r];
        }
      }
    }
  }
}

// ---------------- combine split-K partials for Wc: out = relu(p0+p1+bias)
__global__ __launch_bounds__(256) void k_combine(const float* __restrict__ p,
                                                 const float* __restrict__ bc,
                                                 float* __restrict__ out) {
  size_t i4 = ((size_t)blockIdx.x * 256 + threadIdx.x) * 4;  // over 512*8192
  int co = (int)(i4 >> 13);
  int ng = (int)(i4 & 8191);
  f32x4 v = *(const f32x4*)(p + (size_t)co * 8192 + ng) +
            *(const f32x4*)(p + (size_t)(512 + co) * 8192 + ng);
  float bb = bc[co];
#pragma unroll
  for (int e = 0; e < 4; e++) {
    float q = v[e] + bb;
    v[e] = q > 0.f ? q : 0.f;
  }
  int batch = ng >> 12, rem = ng & 4095;
  *(f32x4*)(out + ((size_t)(batch * 512 + co)) * 4096 + rem) = v;
}

extern "C" void kernel_launch(void* const* d_in, const int* in_sizes, int n_in,
                              void* d_out, int out_size, void* d_ws, size_t ws_size,
                              hipStream_t stream) {
  const float* x = (const float*)d_in[0];
  const float* Wg = (const float*)d_in[1];
  const float* bg = (const float*)d_in[2];
  const float* Wd = (const float*)d_in[3];
  const float* bd = (const float*)d_in[4];
  const float* Wc = (const float*)d_in[5];
  const float* bc = (const float*)d_in[6];
  float* out = (float*)d_out;

  char* ws = (char*)d_ws;
  size_t off = 0;
  auto alloc = [&](size_t bytes) {
    void* p = ws + off;
    off = (off + bytes + 255) & ~(size_t)255;
    return p;
  };
  const size_t SZ_WDT = (size_t)2048 * 9216 * 2;      // 37.75 MB
  const size_t SZ_WCT = (size_t)512 * 18432 * 2;      // 18.87 MB
  const size_t SZ_WGT = (size_t)4 * 2 * 9 * 1024 * 4;
  const size_t SZ_CP = (size_t)2 * 66 * 66 * 512 * 2;      // 8.92 MB
  const size_t SZ_NF = (size_t)4 * 2 * 66 * 66 * 512 * 2;  // 35.68 MB
  const size_t SZ_GT = (size_t)2 * 66 * 66 * 2048 * 2;     // 35.68 MB
  const size_t SZ_GW = (size_t)4 * 2 * 2 * 4096 * 4;
  const size_t SZ_CORR = (size_t)4 * 2 * 25 * 4096 * 4;    // 3.28 MB
  const size_t SZ_CPART = SZ_CORR * 4;                      // 13.11 MB
  const size_t SZ_FG1 = (size_t)2 * 66 * 66 * 1024 * 2;    // 17.84 MB
  const size_t SZ_FG4 = SZ_FG1 * 4;                         // 71.37 MB
  const size_t SZ_WCP = (size_t)2 * 512 * 8192 * 4;        // 33.55 MB

  unsigned short* WdT = (unsigned short*)alloc(SZ_WDT);
  unsigned short* WcT = (unsigned short*)alloc(SZ_WCT);
  float* WgT = (float*)alloc(SZ_WGT);
  unsigned short* centerpad = (unsigned short*)alloc(SZ_CP);
  unsigned short* nfpad = (unsigned short*)alloc(SZ_NF);
  unsigned short* gatedpad = (unsigned short*)alloc(SZ_GT);
  float* gw = (float*)alloc(SZ_GW);
  unsigned* maxb = (unsigned*)alloc(256);

  // union region: corr+cpart (phase 1) -> fg (phase 2) -> Wc partials (phase 3)
  size_t unionOff = off;
  size_t needBatched = unionOff + SZ_FG4 + 4096;  // FG4 is the largest occupant
  bool batched = ws_size >= needBatched;

  float* corr = (float*)(ws + unionOff);
  float* cpart = (float*)(ws + unionOff + ((SZ_CORR + 255) & ~(size_t)255));
  unsigned short* fg = (unsigned short*)(ws + unionOff);
  float* wcp = (float*)(ws + unionOff);
  size_t fgBytes = batched ? SZ_FG4 : SZ_FG1;

  hipMemsetAsync(centerpad, 0, SZ_CP, stream);
  hipMemsetAsync(nfpad, 0, SZ_NF, stream);
  hipMemsetAsync(gatedpad, 0, SZ_GT, stream);
  hipMemsetAsync(maxb, 0, 64, stream);

  k_reorder_w<<<4096, 256, 0, stream>>>(Wd, WdT, 10, (long)2048 * 9216);
  k_reorder_w<<<4096, 256, 0, stream>>>(Wc, WcT, 11, (long)512 * 18432);
  k_reorder_wg<<<288, 256, 0, stream>>>(Wg, WgT);
  k_centerpad<<<dim3(64, 2), 256, 0, stream>>>(x, centerpad);
  k_corr<<<dim3(4, 4, 32), 256, 0, stream>>>(x, cpart);
  k_corr_combine<<<dim3(200, 4), 256, 0, stream>>>(cpart, corr, maxb);
  k_attn_nf<<<dim3(4, 4, 32), 256, 0, stream>>>(x, corr, maxb, nfpad);
  k_gate2<<<dim3(8, 64, 8), 256, 0, stream>>>(centerpad, nfpad, WgT, bg, gw);

  // corr/cpart dead now; reuse region for fg
  hipMemsetAsync(fg, 0, fgBytes, stream);

  if (batched) {
    k_fg<<<dim3(4096, 4), 256, 0, stream>>>(centerpad, nfpad, gw, fg, 0);
    conv128<1024, 0><<<dim3(256, 4), 256, 0, stream>>>(fg, WdT, bd, gatedpad, nullptr);
    conv128<2048, 2><<<dim3(256, 2), 256, 0, stream>>>(gatedpad, WcT, nullptr, nullptr, wcp);
    k_combine<<<4096, 256, 0, stream>>>(wcp, bc, out);
  } else {
    for (int pair = 0; pair < 4; ++pair) {
      k_fg<<<dim3(4096, 1), 256, 0, stream>>>(centerpad, nfpad, gw, fg, pair);
      conv128<1024, 0><<<dim3(256, 1), 256, 0, stream>>>(
          fg, WdT + (size_t)pair * 512 * 9216, bd + pair * 512, gatedpad + pair * 512,
          nullptr);
    }
    conv128<2048, 1><<<dim3(256, 1), 256, 0, stream>>>(gatedpad, WcT, bc, nullptr, out);
  }
}

// Round 3
// 1122.225 us; speedup vs baseline: 1.4428x; 1.1384x over previous
//
#include <hip/hip_runtime.h>
#include <hip/hip_bf16.h>
#include <stdint.h>

typedef __attribute__((ext_vector_type(8))) short bf16x8;
typedef __attribute__((ext_vector_type(4))) float f32x4;
typedef __attribute__((ext_vector_type(4))) int int4v;

#define DEVI static __device__ __forceinline__

DEVI unsigned short f2b(float f) {
  union { float f; unsigned u; } v; v.f = f;
  unsigned r = (v.u + 0x7FFFu + ((v.u >> 16) & 1u)) >> 16;
  return (unsigned short)r;
}
DEVI float b2f(unsigned short h) {
  union { unsigned u; float f; } v; v.u = ((unsigned)h) << 16;
  return v.f;
}
DEVI unsigned encf(float f) {
  union { float f; unsigned u; } v; v.f = f;
  return (v.u & 0x80000000u) ? ~v.u : (v.u | 0x80000000u);
}
DEVI float decf(unsigned u) {
  union { unsigned u; float f; } v;
  v.u = (u & 0x80000000u) ? (u & 0x7FFFFFFFu) : ~u;
  return v.f;
}
DEVI void gload16(const void* g, void* l) {
  __builtin_amdgcn_global_load_lds(
      (const __attribute__((address_space(1))) unsigned int*)g,
      (__attribute__((address_space(3))) unsigned int*)l, 16, 0, 0);
}

// ---------------- weight reorder: dst[r][tap][ci] bf16 <- src[r][ci][tap] f32
__global__ void k_reorder_w(const float* __restrict__ src, unsigned short* __restrict__ dst,
                            int lgCI, long total) {
  int CI = 1 << lgCI;
  for (long idx = (long)blockIdx.x * 256 + threadIdx.x; idx < total;
       idx += (long)gridDim.x * 256) {
    int ci = (int)(idx & (CI - 1));
    int rt = (int)(idx >> lgCI);
    int tap = rt % 9;
    int r = rt / 9;
    dst[idx] = f2b(src[((size_t)r * CI + ci) * 9 + tap]);
  }
}

// WgT[p][o][tap][ci] f32 <- Wg[p][o][ci][tap]
__global__ void k_reorder_wg(const float* __restrict__ src, float* __restrict__ dst) {
  int idx = blockIdx.x * 256 + threadIdx.x;  // total 73728
  int ci = idx & 1023;
  int rt = idx >> 10;
  int tap = rt % 9;
  int po = rt / 9;
  dst[idx] = src[((size_t)po * 1024 + ci) * 9 + tap];
}

// ---------------- pad/transpose: x NCHW f32 -> NHWC bf16
// frames {0,1,3,4} -> xf1[fi][b][68][68][512] (pad 2); frame 2 -> cp[b][66][66][512] (pad 1)
__global__ __launch_bounds__(256) void k_pad(const float* __restrict__ xin,
                                             unsigned short* __restrict__ xf1,
                                             unsigned short* __restrict__ cp) {
  __shared__ unsigned short lds[64 * 66];
  int t = threadIdx.x;
  int y = blockIdx.x;   // 0..63
  int fb = blockIdx.y;  // 0..9 = f*2+b
  int f = fb >> 1, b = fb & 1;
  const float* src = xin + (size_t)fb * 512 * 4096 + y * 64;
  unsigned short* base;
  if (f == 2) {
    base = cp + (((size_t)b * 66) + y + 1) * 66 * 512 + 512;
  } else {
    int fi = f < 2 ? f : f - 1;
    base = xf1 + (((size_t)(fi * 2 + b) * 68) + y + 2) * 68 * 512 + 2 * 512;
  }
  for (int c0 = 0; c0 < 512; c0 += 64) {
#pragma unroll
    for (int r = 0; r < 16; ++r) {
      int ci = r * 4 + (t >> 6);
      int xx = t & 63;
      lds[ci * 66 + xx] = f2b(src[(size_t)(c0 + ci) * 4096 + xx]);
    }
    __syncthreads();
    int xp = t >> 2;
    int cc = (t & 3) * 16;
    __align__(16) unsigned short vals[16];
#pragma unroll
    for (int i = 0; i < 16; i++) vals[i] = lds[(cc + i) * 66 + xp];
    unsigned short* dst = base + (size_t)xp * 512 + c0 + cc;
    *(int4v*)(dst) = *(const int4v*)(vals);
    *(int4v*)(dst + 8) = *(const int4v*)(vals + 8);
    __syncthreads();
  }
}

// ---------------- correlation partials (f32, exact): corrpart[part][pair][b][25][64][64]
__global__ __launch_bounds__(256) void k_corr(const float* __restrict__ xin,
                                              float* __restrict__ corrpart) {
  __shared__ float f1h[2][20][21];
  int t = threadIdx.x;
  int tx = t & 15, ty = t >> 4;
  int x0 = blockIdx.x * 16, y0 = blockIdx.y * 16;
  int z = blockIdx.z;
  int b = z & 1, pair = (z >> 1) & 3, part = z >> 3;
  int s = pair < 2 ? pair : pair + 1;
  const float* f2 = xin + ((size_t)(2 * 2 + b) * 512) * 4096;
  const float* f1 = xin + ((size_t)(s * 2 + b) * 512) * 4096;
  float acc[25];
#pragma unroll
  for (int d = 0; d < 25; d++) acc[d] = 0.f;
  int y = y0 + ty, x = x0 + tx;
  for (int c = part * 128; c < part * 128 + 128; c += 2) {
    for (int k = t; k < 800; k += 256) {
      int ch = k / 400, e = k - ch * 400;
      int r = e / 20, ccx = e - r * 20;
      int gy = y0 + r - 2, gx = x0 + ccx - 2;
      float v = 0.f;
      if ((unsigned)gy < 64u && (unsigned)gx < 64u)
        v = f1[(size_t)(c + ch) * 4096 + gy * 64 + gx];
      f1h[ch][r][ccx] = v;
    }
    float f2a = f2[(size_t)c * 4096 + y * 64 + x];
    float f2c = f2[(size_t)(c + 1) * 4096 + y * 64 + x];
    __syncthreads();
#pragma unroll
    for (int d = 0; d < 25; ++d) {
      int di = d / 5, dj = d % 5;
      acc[d] += f2a * f1h[0][ty + di][tx + dj] + f2c * f1h[1][ty + di][tx + dj];
    }
    __syncthreads();
  }
  float* out = corrpart + ((size_t)((part * 4 + pair) * 2 + b) * 25) * 4096;
#pragma unroll
  for (int d = 0; d < 25; d++) out[(size_t)d * 4096 + y * 64 + x] = acc[d];
}

// ---------------- combine partials + global max per pair
__global__ __launch_bounds__(256) void k_corr_combine(const float* __restrict__ cpart,
                                                      float* __restrict__ corr,
                                                      unsigned* __restrict__ maxb) {
  const size_t PERPAIR = (size_t)2 * 25 * 4096;
  int pair = blockIdx.y;
  size_t i4 = ((size_t)blockIdx.x * 256 + threadIdx.x) * 4;
  f32x4 sacc = {0.f, 0.f, 0.f, 0.f};
#pragma unroll
  for (int p = 0; p < 4; p++)
    sacc += *(const f32x4*)(cpart + ((size_t)(p * 4 + pair)) * PERPAIR + i4);
  *(f32x4*)(corr + (size_t)pair * PERPAIR + i4) = sacc;
  float m = fmaxf(fmaxf(sacc[0], sacc[1]), fmaxf(sacc[2], sacc[3]));
#pragma unroll
  for (int off = 32; off; off >>= 1) m = fmaxf(m, __shfl_xor(m, off));
  __shared__ float wm[4];
  if ((threadIdx.x & 63) == 0) wm[threadIdx.x >> 6] = m;
  __syncthreads();
  if (threadIdx.x == 0) {
    float mm = fmaxf(fmaxf(wm[0], wm[1]), fmaxf(wm[2], wm[3]));
    atomicMax(maxb + pair, encf(mm));
  }
}

// ---------------- softmax + 5x5 gather from bf16 NHWC -> nfpad [pair][b][66][66][512]
__global__ __launch_bounds__(256) void k_attn3(const unsigned short* __restrict__ xf1,
                                               const float* __restrict__ corr,
                                               const unsigned* __restrict__ maxb,
                                               unsigned short* __restrict__ nfpad) {
  __shared__ unsigned short f1t[400 * 8];
  int t = threadIdx.x;
  int tx = t & 15, ty = t >> 4;
  int x0 = blockIdx.x * 16, y0 = blockIdx.y * 16;
  int z = blockIdx.z;  // b + 2*pair + 8*cgh
  int b = z & 1, pair = (z >> 1) & 3, cgh = z >> 3;
  const unsigned short* f1 = xf1 + ((size_t)(pair * 2 + b)) * 68 * 68 * 512;
  int y = y0 + ty, x = x0 + tx;
  const float* cr = corr + ((size_t)(pair * 2 + b)) * 25 * 4096 + y * 64 + x;
  float p[25];
  float mx = -1e30f;
#pragma unroll
  for (int d = 0; d < 25; d++) {
    p[d] = cr[(size_t)d * 4096];
    mx = fmaxf(mx, p[d]);
  }
  float gs = 20.f / decf(maxb[pair]);
  float ss = 0.f;
#pragma unroll
  for (int d = 0; d < 25; d++) {
    p[d] = __expf((p[d] - mx) * gs);
    ss += p[d];
  }
  float inv = 1.f / ss;
#pragma unroll
  for (int d = 0; d < 25; d++) p[d] *= inv;

  for (int cg = cgh * 32; cg < cgh * 32 + 32; ++cg) {
    for (int k = t; k < 400; k += 256) {
      int r = k / 20, c = k - r * 20;
      *(int4v*)&f1t[k * 8] =
          *(const int4v*)&f1[((size_t)(y0 + r) * 68 + (x0 + c)) * 512 + cg * 8];
    }
    __syncthreads();
    float acc[8] = {0.f, 0.f, 0.f, 0.f, 0.f, 0.f, 0.f, 0.f};
#pragma unroll
    for (int d = 0; d < 25; d++) {
      bf16x8 v = *(const bf16x8*)&f1t[((ty + d / 5) * 20 + tx + d % 5) * 8];
      float pd = p[d];
#pragma unroll
      for (int e = 0; e < 8; e++) acc[e] += pd * b2f((unsigned short)v[e]);
    }
    __align__(16) unsigned short o[8];
#pragma unroll
    for (int e = 0; e < 8; e++) o[e] = f2b(acc[e]);
    *(int4v*)&nfpad[(((size_t)(pair * 2 + b) * 66 + (y + 1)) * 66 + (x + 1)) * 512 +
                    cg * 8] = *(const int4v*)o;
    __syncthreads();
  }
}

// ---------------- gate conv (f32 accum, bf16 acts)
__global__ __launch_bounds__(256) void k_gate2(const unsigned short* __restrict__ cp,
                                               const unsigned short* __restrict__ nfp,
                                               const float* __restrict__ wgt,
                                               const float* __restrict__ bg,
                                               float* __restrict__ gw) {
  int t = threadIdx.x;
  int z = blockIdx.z;
  int b = z & 1, pair = z >> 1;
  int y = blockIdx.y;
  int x = blockIdx.x * 8 + (t >> 5);
  int chunk = t & 31;
  int ci0 = chunk * 32;
  int half = ci0 >> 9;
  int ch0 = ci0 & 511;
  const unsigned short* src = half ? (nfp + ((size_t)(pair * 2 + b)) * 66 * 66 * 512)
                                   : (cp + ((size_t)b) * 66 * 66 * 512);
  const float* w = wgt + (size_t)pair * 2 * 9 * 1024;
  float a0 = 0.f, a1 = 0.f, a0b = 0.f, a1b = 0.f;
  for (int tap = 0; tap < 9; ++tap) {
    int ky = tap / 3, kx = tap % 3;
    const unsigned short* ip = src + ((size_t)(y + ky) * 66 + (x + kx)) * 512 + ch0;
    const float* w0 = w + ((size_t)0 * 9 + tap) * 1024 + ci0;
    const float* w1 = w + ((size_t)1 * 9 + tap) * 1024 + ci0;
#pragma unroll
    for (int q = 0; q < 4; ++q) {
      bf16x8 v8 = *(const bf16x8*)(ip + q * 8);
      f32x4 wa = *(const f32x4*)(w0 + q * 8);
      f32x4 wb = *(const f32x4*)(w0 + q * 8 + 4);
      f32x4 wc = *(const f32x4*)(w1 + q * 8);
      f32x4 wd = *(const f32x4*)(w1 + q * 8 + 4);
#pragma unroll
      for (int e = 0; e < 4; e++) {
        float f0 = b2f((unsigned short)v8[e]);
        float f1v = b2f((unsigned short)v8[e + 4]);
        a0 += f0 * wa[e];
        a0b += f1v * wb[e];
        a1 += f0 * wc[e];
        a1b += f1v * wd[e];
      }
    }
  }
  a0 += a0b;
  a1 += a1b;
#pragma unroll
  for (int md = 1; md < 32; md <<= 1) {
    a0 += __shfl_xor(a0, md);
    a1 += __shfl_xor(a1, md);
  }
  if ((t & 31) == 0) {
    float g0 = 1.f / (1.f + __expf(-(a0 + bg[pair * 2 + 0])));
    float g1 = 1.f / (1.f + __expf(-(a1 + bg[pair * 2 + 1])));
    gw[(((size_t)(pair * 2 + b) * 2 + 0) * 64 + y) * 64 + x] = g0;
    gw[(((size_t)(pair * 2 + b) * 2 + 1) * 64 + y) * 64 + x] = g1;
  }
}

// ---------------- fg = [center*g0, nf*g1] -> fgp[pz][2][66][66][1024] bf16
__global__ __launch_bounds__(256) void k_fg(const unsigned short* __restrict__ cp,
                                            const unsigned short* __restrict__ nfp,
                                            const float* __restrict__ gw,
                                            unsigned short* __restrict__ fgp, int pairBase) {
  int pz = blockIdx.y;
  int pair = pairBase + pz;
  unsigned short* dstBase = fgp + (size_t)pz * 2 * 66 * 66 * 1024;
  size_t idx = (size_t)blockIdx.x * 256 + threadIdx.x;
  int chunk = (int)(idx & 127);
  size_t px = idx >> 7;
  int b = (int)(px >> 12), rem = (int)(px & 4095);
  int y = rem >> 6, x = rem & 63;
  int ci0 = chunk * 8;
  int half = ci0 >> 9;
  float g = gw[(((size_t)(pair * 2 + b) * 2 + half) * 64 + y) * 64 + x];
  const unsigned short* src = half ? (nfp + ((size_t)(pair * 2 + b)) * 66 * 66 * 512)
                                   : (cp + (size_t)b * 66 * 66 * 512);
  size_t poff = ((size_t)(y + 1) * 66 + (x + 1)) * 512 + (ci0 - half * 512);
  bf16x8 v = *(const bf16x8*)(src + poff);
  __align__(16) unsigned short o[8];
#pragma unroll
  for (int e = 0; e < 8; e++) o[e] = f2b(b2f((unsigned short)v[e]) * g);
  *(int4v*)(dstBase + ((size_t)(b * 66 + y + 1) * 66 + (x + 1)) * 1024 + ci0) =
      *(const int4v*)o;
}

// ---------------- 256x256x64 pipelined implicit-GEMM conv, 512 thr, 8 waves (2Mx4N)
// 4 phases per K-tile; stages for kt+1 issued at phases 0-1; vmcnt(0) at phase 3.
// MODE 0: Wd (z=pair or pairOfs), bf16 out to gatedpad (+bias+relu)
// MODE 2: Wc split-K over z (KTOT/4 each), bf16 partials [z][512][8192]
template <int CI, int MODE>
__global__ __launch_bounds__(512, 2) void conv256(const unsigned short* __restrict__ inB,
                                                  const unsigned short* __restrict__ WTb,
                                                  const float* __restrict__ bias,
                                                  unsigned short* __restrict__ outB,
                                                  unsigned short* __restrict__ outP,
                                                  int pairOfs) {
  constexpr int K = 9 * CI;
  constexpr int KTOT = K / 64;
  constexpr int KT = (MODE == 2) ? KTOT / 4 : KTOT;
  __shared__ unsigned short As[2][256 * 64];
  __shared__ unsigned short Bs[2][256 * 64];

  int t = threadIdx.x;
  int z = blockIdx.y;
  const unsigned short* inPad = (MODE == 0) ? inB + (size_t)z * 2 * 66 * 66 * 1024 : inB;
  const unsigned short* WT = (MODE == 0) ? WTb + (size_t)z * 512 * 9216 : WTb;
  const int kt0 = (MODE == 2) ? z * KT : 0;
  const int ktEnd = kt0 + KT;

  int xb = blockIdx.x;  // 64 tiles: m = xb>>5, n = xb&31 (B-tiles XCD-local)
  int m = xb >> 5, n = xb & 31;
  int co0 = m * 256, n0 = n * 256;

  // staging thread geometry: idx = rr*512 + t -> row_local = idx>>3 (0..127), col8 = idx&7
  int lr[2], c8_[2], cg[2];
  int aoff[2][2];   // [half][rr]
  int boff[2][2];
#pragma unroll
  for (int rr = 0; rr < 2; rr++) {
    int idx = rr * 512 + t;
    lr[rr] = idx >> 3;
    c8_[rr] = idx & 7;
    cg[rr] = c8_[rr] ^ (lr[rr] & 7);
#pragma unroll
    for (int h = 0; h < 2; h++) {
      int row = h * 128 + lr[rr];
      aoff[h][rr] = (co0 + row) * K + cg[rr] * 8;
      int ng = n0 + row;
      int bb = ng >> 12, yy = (ng >> 6) & 63, xx = ng & 63;
      boff[h][rr] = ((bb * 66 + yy) * 66 + xx) * CI + cg[rr] * 8;
    }
  }

  f32x4 acc[8][4];
#pragma unroll
  for (int i = 0; i < 8; i++)
#pragma unroll
    for (int j = 0; j < 4; j++) acc[i][j] = f32x4{0.f, 0.f, 0.f, 0.f};

  int wid = t >> 6, l = t & 63;
  int wm = wid >> 2, wn = wid & 3;
  int lrow = l & 15, lk4 = l >> 4;

  bf16x8 af[4][2], bf[2][2];

  auto STA = [&](int buf, int kt, int h) {
#pragma unroll
    for (int rr = 0; rr < 2; rr++)
      gload16(WT + (size_t)aoff[h][rr] + kt * 64, &As[buf][h * 8192 + (rr * 512 + t) * 8]);
  };
  auto STB = [&](int buf, int kt, int h) {
    int tap = (CI == 1024) ? (kt >> 4) : (kt >> 5);
    int kci = (CI == 1024) ? ((kt & 15) << 6) : ((kt & 31) << 6);
    int ky = tap / 3, kx = tap - ky * 3;
    int toff = (ky * 66 + kx) * CI + kci;
#pragma unroll
    for (int rr = 0; rr < 2; rr++)
      gload16(inPad + (size_t)boff[h][rr] + toff, &Bs[buf][h * 8192 + (rr * 512 + t) * 8]);
  };
  auto RA = [&](int buf, int mh) {
#pragma unroll
    for (int ii = 0; ii < 4; ii++) {
      int row = wm * 128 + mh * 64 + ii * 16 + lrow;
#pragma unroll
      for (int kk = 0; kk < 2; kk++) {
        int c8 = (kk * 4 + lk4) ^ (lrow & 7);
        af[ii][kk] = *(const bf16x8*)&As[buf][row * 64 + c8 * 8];
      }
    }
  };
  auto RB = [&](int buf, int nh) {
#pragma unroll
    for (int j = 0; j < 2; j++) {
      int row = wn * 64 + nh * 32 + j * 16 + lrow;
#pragma unroll
      for (int kk = 0; kk < 2; kk++) {
        int c8 = (kk * 4 + lk4) ^ (lrow & 7);
        bf[j][kk] = *(const bf16x8*)&Bs[buf][row * 64 + c8 * 8];
      }
    }
  };

#define MFMA_QUAD(MH, NH)                                                        \
  __builtin_amdgcn_s_setprio(1);                                                 \
  _Pragma("unroll") for (int ii = 0; ii < 4; ++ii) {                             \
    _Pragma("unroll") for (int j = 0; j < 2; ++j) {                              \
      _Pragma("unroll") for (int kk = 0; kk < 2; ++kk) {                         \
        acc[(MH)*4 + ii][(NH)*2 + j] = __builtin_amdgcn_mfma_f32_16x16x32_bf16(  \
            af[ii][kk], bf[j][kk], acc[(MH)*4 + ii][(NH)*2 + j], 0, 0, 0);       \
      }                                                                          \
    }                                                                            \
  }                                                                              \
  __builtin_amdgcn_s_setprio(0);

  // prologue: stage K-tile kt0 fully, drain, barrier
  {
    int buf = kt0 & 1;
    STA(buf, kt0, 0);
    STA(buf, kt0, 1);
    STB(buf, kt0, 0);
    STB(buf, kt0, 1);
    asm volatile("s_waitcnt vmcnt(0)" ::: "memory");
    __builtin_amdgcn_s_barrier();
  }

  for (int kt = kt0; kt < ktEnd; ++kt) {
    int cur = kt & 1, nxt = cur ^ 1;
    const bool pf = (kt + 1 < ktEnd);
    // P0: (mh0, nh0) — read A-half0 frags + B-half0 frags; stage next A
    RA(cur, 0);
    RB(cur, 0);
    if (pf) {
      STA(nxt, kt + 1, 0);
      STA(nxt, kt + 1, 1);
    }
    __builtin_amdgcn_s_barrier();
    asm volatile("s_waitcnt lgkmcnt(0)" ::: "memory");
    __builtin_amdgcn_sched_barrier(0);
    MFMA_QUAD(0, 0)
    __builtin_amdgcn_s_barrier();
    // P1: (mh1, nh0) — reuse bf; stage next B
    RA(cur, 1);
    if (pf) {
      STB(nxt, kt + 1, 0);
      STB(nxt, kt + 1, 1);
    }
    __builtin_amdgcn_s_barrier();
    asm volatile("s_waitcnt lgkmcnt(0)" ::: "memory");
    __builtin_amdgcn_sched_barrier(0);
    MFMA_QUAD(1, 0)
    __builtin_amdgcn_s_barrier();
    // P2: (mh1, nh1) — reuse af
    RB(cur, 1);
    __builtin_amdgcn_s_barrier();
    asm volatile("s_waitcnt lgkmcnt(0)" ::: "memory");
    __builtin_amdgcn_sched_barrier(0);
    MFMA_QUAD(1, 1)
    __builtin_amdgcn_s_barrier();
    // P3: (mh0, nh1) — reuse bf
    RA(cur, 0);
    __builtin_amdgcn_s_barrier();
    asm volatile("s_waitcnt lgkmcnt(0)" ::: "memory");
    __builtin_amdgcn_sched_barrier(0);
    MFMA_QUAD(0, 1)
    asm volatile("s_waitcnt vmcnt(0)" ::: "memory");
    __builtin_amdgcn_s_barrier();
  }
#undef MFMA_QUAD

  int lks = lk4;
#pragma unroll
  for (int i = 0; i < 8; i++) {
#pragma unroll
    for (int j = 0; j < 4; j++) {
      int col = wn * 64 + j * 16 + lrow;
      int ng = n0 + col;
      int bb = ng >> 12, yy = (ng >> 6) & 63, xx = ng & 63;
#pragma unroll
      for (int r = 0; r < 4; r++) {
        int row = wm * 128 + i * 16 + lks * 4 + r;
        int co = co0 + row;
        if (MODE == 0) {
          int zc = (z + pairOfs) * 512 + co;
          float v = acc[i][j][r] + bias[zc];
          v = v > 0.f ? v : 0.f;
          outB[((size_t)(bb * 66 + yy + 1) * 66 + (xx + 1)) * 2048 + zc] = f2b(v);
        } else {
          outP[((size_t)(z * 512 + co) << 13) + ng] = f2b(acc[i][j][r]);
        }
      }
    }
  }
}

// ---------------- combine split-K bf16 partials: out = relu(sum + bias), f32 NCHW
__global__ __launch_bounds__(256) void k_combine2(const unsigned short* __restrict__ p,
                                                  const float* __restrict__ bc,
                                                  float* __restrict__ out) {
  size_t i8 = ((size_t)blockIdx.x * 256 + threadIdx.x) * 8;  // over 512*8192
  int co = (int)(i8 >> 13);
  int ng = (int)(i8 & 8191);
  float s[8] = {0.f, 0.f, 0.f, 0.f, 0.f, 0.f, 0.f, 0.f};
#pragma unroll
  for (int zz = 0; zz < 4; zz++) {
    bf16x8 v = *(const bf16x8*)&p[((size_t)(zz * 512 + co) << 13) + ng];
#pragma unroll
    for (int e = 0; e < 8; e++) s[e] += b2f((unsigned short)v[e]);
  }
  float bb = bc[co];
  int batch = ng >> 12, rem = ng & 4095;
  float* o = out + (((size_t)(batch * 512 + co)) << 12) + rem;
#pragma unroll
  for (int e = 0; e < 8; e++) {
    float q = s[e] + bb;
    o[e] = q > 0.f ? q : 0.f;
  }
}

extern "C" void kernel_launch(void* const* d_in, const int* in_sizes, int n_in,
                              void* d_out, int out_size, void* d_ws, size_t ws_size,
                              hipStream_t stream) {
  const float* x = (const float*)d_in[0];
  const float* Wg = (const float*)d_in[1];
  const float* bg = (const float*)d_in[2];
  const float* Wd = (const float*)d_in[3];
  const float* bd = (const float*)d_in[4];
  const float* Wc = (const float*)d_in[5];
  const float* bc = (const float*)d_in[6];
  float* out = (float*)d_out;

  char* ws = (char*)d_ws;
  size_t off = 0;
  auto alloc = [&](size_t bytes) {
    void* p = ws + off;
    off = (off + bytes + 255) & ~(size_t)255;
    return p;
  };
  const size_t SZ_WDT = (size_t)2048 * 9216 * 2;
  const size_t SZ_WCT = (size_t)512 * 18432 * 2;
  const size_t SZ_WGT = (size_t)4 * 2 * 9 * 1024 * 4;
  const size_t SZ_CP = (size_t)2 * 66 * 66 * 512 * 2;
  const size_t SZ_NF = (size_t)4 * 2 * 66 * 66 * 512 * 2;
  const size_t SZ_GT = (size_t)2 * 66 * 66 * 2048 * 2;
  const size_t SZ_GW = (size_t)4 * 2 * 2 * 4096 * 4;
  const size_t SZ_XF1 = (size_t)4 * 2 * 68 * 68 * 512 * 2;   // 37.9 MB
  const size_t SZ_CORR = (size_t)4 * 2 * 25 * 4096 * 4;      // 3.3 MB
  const size_t SZ_CPART = SZ_CORR * 4;                        // 13.1 MB
  const size_t SZ_FG1 = (size_t)2 * 66 * 66 * 1024 * 2;      // 17.8 MB
  const size_t SZ_FG4 = SZ_FG1 * 4;                           // 71.4 MB
  const size_t SZ_WCP = (size_t)4 * 512 * 8192 * 2;          // 33.6 MB

  unsigned short* WdT = (unsigned short*)alloc(SZ_WDT);
  unsigned short* WcT = (unsigned short*)alloc(SZ_WCT);
  float* WgT = (float*)alloc(SZ_WGT);
  unsigned short* centerpad = (unsigned short*)alloc(SZ_CP);
  unsigned short* nfpad = (unsigned short*)alloc(SZ_NF);
  unsigned short* gatedpad = (unsigned short*)alloc(SZ_GT);
  float* gw = (float*)alloc(SZ_GW);
  unsigned* maxb = (unsigned*)alloc(256);

  // union region: phase1 {xf1, corr, cpart} -> phase2 {fg} -> phase3 {wcp}
  size_t unionOff = off;
  unsigned short* xf1 = (unsigned short*)(ws + unionOff);
  size_t o2 = unionOff + ((SZ_XF1 + 255) & ~(size_t)255);
  float* corr = (float*)(ws + o2);
  float* cpart = (float*)(ws + o2 + ((SZ_CORR + 255) & ~(size_t)255));
  unsigned short* fg = (unsigned short*)(ws + unionOff);
  unsigned short* wcp = (unsigned short*)(ws + unionOff);
  bool batched = ws_size >= unionOff + SZ_FG4;
  size_t fgBytes = batched ? SZ_FG4 : SZ_FG1;

  hipMemsetAsync(centerpad, 0, SZ_CP, stream);
  hipMemsetAsync(nfpad, 0, SZ_NF, stream);
  hipMemsetAsync(gatedpad, 0, SZ_GT, stream);
  hipMemsetAsync(maxb, 0, 64, stream);
  hipMemsetAsync(xf1, 0, SZ_XF1, stream);

  k_reorder_w<<<4096, 256, 0, stream>>>(Wd, WdT, 10, (long)2048 * 9216);
  k_reorder_w<<<4096, 256, 0, stream>>>(Wc, WcT, 11, (long)512 * 18432);
  k_reorder_wg<<<288, 256, 0, stream>>>(Wg, WgT);
  k_pad<<<dim3(64, 10), 256, 0, stream>>>(x, xf1, centerpad);
  k_corr<<<dim3(4, 4, 32), 256, 0, stream>>>(x, cpart);
  k_corr_combine<<<dim3(200, 4), 256, 0, stream>>>(cpart, corr, maxb);
  k_attn3<<<dim3(4, 4, 16), 256, 0, stream>>>(xf1, corr, maxb, nfpad);
  k_gate2<<<dim3(8, 64, 8), 256, 0, stream>>>(centerpad, nfpad, WgT, bg, gw);

  // xf1/corr/cpart dead now; reuse union region for fg
  hipMemsetAsync(fg, 0, fgBytes, stream);

  if (batched) {
    k_fg<<<dim3(4096, 4), 256, 0, stream>>>(centerpad, nfpad, gw, fg, 0);
    conv256<1024, 0><<<dim3(64, 4), 512, 0, stream>>>(fg, WdT, bd, gatedpad, nullptr, 0);
  } else {
    for (int pair = 0; pair < 4; ++pair) {
      k_fg<<<dim3(4096, 1), 256, 0, stream>>>(centerpad, nfpad, gw, fg, pair);
      conv256<1024, 0><<<dim3(64, 1), 512, 0, stream>>>(
          fg, WdT + (size_t)pair * 512 * 9216, bd, gatedpad, nullptr, pair);
    }
  }
  conv256<2048, 2><<<dim3(64, 4), 512, 0, stream>>>(gatedpad, WcT, nullptr, nullptr, wcp, 0);
  k_combine2<<<2048, 256, 0, stream>>>(wcp, bc, out);
}

// Round 4
// 1074.571 us; speedup vs baseline: 1.5068x; 1.0443x over previous
//
#include <hip/hip_runtime.h>
#include <hip/hip_bf16.h>
#include <stdint.h>

typedef __attribute__((ext_vector_type(8))) short bf16x8;
typedef __attribute__((ext_vector_type(4))) float f32x4;
typedef __attribute__((ext_vector_type(4))) int int4v;

#define DEVI static __device__ __forceinline__

DEVI unsigned short f2b(float f) {
  union { float f; unsigned u; } v; v.f = f;
  unsigned r = (v.u + 0x7FFFu + ((v.u >> 16) & 1u)) >> 16;
  return (unsigned short)r;
}
DEVI float b2f(unsigned short h) {
  union { unsigned u; float f; } v; v.u = ((unsigned)h) << 16;
  return v.f;
}
DEVI unsigned encf(float f) {
  union { float f; unsigned u; } v; v.f = f;
  return (v.u & 0x80000000u) ? ~v.u : (v.u | 0x80000000u);
}
DEVI float decf(unsigned u) {
  union { unsigned u; float f; } v;
  v.u = (u & 0x80000000u) ? (u & 0x7FFFFFFFu) : ~u;
  return v.f;
}
DEVI void gload16(const void* g, void* l) {
  __builtin_amdgcn_global_load_lds(
      (const __attribute__((address_space(1))) unsigned int*)g,
      (__attribute__((address_space(3))) unsigned int*)l, 16, 0, 0);
}

// ---------------- weight reorder v2 (coalesced): dst[r][tap][ci] <- src[r][ci][tap]
// one block per output row r; thread reads 9 consecutive f32, writes 9 coalesced stores
__global__ __launch_bounds__(256) void k_reorder_w2(const float* __restrict__ src,
                                                    unsigned short* __restrict__ dst,
                                                    int CI) {
  int r = blockIdx.x;
  int t = threadIdx.x;
  const float* s = src + (size_t)r * CI * 9;
  unsigned short* d = dst + (size_t)r * CI * 9;
  for (int ci0 = 0; ci0 < CI; ci0 += 256) {
    int ci = ci0 + t;
    float v[9];
#pragma unroll
    for (int k = 0; k < 9; k++) v[k] = s[(size_t)ci * 9 + k];
#pragma unroll
    for (int k = 0; k < 9; k++) d[(size_t)k * CI + ci] = f2b(v[k]);
  }
}

// WgT[p][o][tap][ci] f32 <- Wg[p][o][ci][tap]
__global__ void k_reorder_wg(const float* __restrict__ src, float* __restrict__ dst) {
  int idx = blockIdx.x * 256 + threadIdx.x;  // total 73728
  int ci = idx & 1023;
  int rt = idx >> 10;
  int tap = rt % 9;
  int po = rt / 9;
  dst[idx] = src[((size_t)po * 1024 + ci) * 9 + tap];
}

// ---------------- pad/transpose: x NCHW f32 -> NHWC bf16
__global__ __launch_bounds__(256) void k_pad(const float* __restrict__ xin,
                                             unsigned short* __restrict__ xf1,
                                             unsigned short* __restrict__ cp) {
  __shared__ unsigned short lds[64 * 66];
  int t = threadIdx.x;
  int y = blockIdx.x;   // 0..63
  int fb = blockIdx.y;  // 0..9 = f*2+b
  int f = fb >> 1, b = fb & 1;
  const float* src = xin + (size_t)fb * 512 * 4096 + y * 64;
  unsigned short* base;
  if (f == 2) {
    base = cp + (((size_t)b * 66) + y + 1) * 66 * 512 + 512;
  } else {
    int fi = f < 2 ? f : f - 1;
    base = xf1 + (((size_t)(fi * 2 + b) * 68) + y + 2) * 68 * 512 + 2 * 512;
  }
  for (int c0 = 0; c0 < 512; c0 += 64) {
#pragma unroll
    for (int r = 0; r < 16; ++r) {
      int ci = r * 4 + (t >> 6);
      int xx = t & 63;
      lds[ci * 66 + xx] = f2b(src[(size_t)(c0 + ci) * 4096 + xx]);
    }
    __syncthreads();
    int xp = t >> 2;
    int cc = (t & 3) * 16;
    __align__(16) unsigned short vals[16];
#pragma unroll
    for (int i = 0; i < 16; i++) vals[i] = lds[(cc + i) * 66 + xp];
    unsigned short* dst = base + (size_t)xp * 512 + c0 + cc;
    *(int4v*)(dst) = *(const int4v*)(vals);
    *(int4v*)(dst + 8) = *(const int4v*)(vals + 8);
    __syncthreads();
  }
}

// ---------------- correlation partials (f32, exact): corrpart[part][pair][b][25][64][64]
__global__ __launch_bounds__(256) void k_corr(const float* __restrict__ xin,
                                              float* __restrict__ corrpart) {
  __shared__ float f1h[2][20][21];
  int t = threadIdx.x;
  int tx = t & 15, ty = t >> 4;
  int x0 = blockIdx.x * 16, y0 = blockIdx.y * 16;
  int z = blockIdx.z;
  int b = z & 1, pair = (z >> 1) & 3, part = z >> 3;
  int s = pair < 2 ? pair : pair + 1;
  const float* f2 = xin + ((size_t)(2 * 2 + b) * 512) * 4096;
  const float* f1 = xin + ((size_t)(s * 2 + b) * 512) * 4096;
  float acc[25];
#pragma unroll
  for (int d = 0; d < 25; d++) acc[d] = 0.f;
  int y = y0 + ty, x = x0 + tx;
  for (int c = part * 128; c < part * 128 + 128; c += 2) {
    for (int k = t; k < 800; k += 256) {
      int ch = k / 400, e = k - ch * 400;
      int r = e / 20, ccx = e - r * 20;
      int gy = y0 + r - 2, gx = x0 + ccx - 2;
      float v = 0.f;
      if ((unsigned)gy < 64u && (unsigned)gx < 64u)
        v = f1[(size_t)(c + ch) * 4096 + gy * 64 + gx];
      f1h[ch][r][ccx] = v;
    }
    float f2a = f2[(size_t)c * 4096 + y * 64 + x];
    float f2c = f2[(size_t)(c + 1) * 4096 + y * 64 + x];
    __syncthreads();
#pragma unroll
    for (int d = 0; d < 25; ++d) {
      int di = d / 5, dj = d % 5;
      acc[d] += f2a * f1h[0][ty + di][tx + dj] + f2c * f1h[1][ty + di][tx + dj];
    }
    __syncthreads();
  }
  float* out = corrpart + ((size_t)((part * 4 + pair) * 2 + b) * 25) * 4096;
#pragma unroll
  for (int d = 0; d < 25; d++) out[(size_t)d * 4096 + y * 64 + x] = acc[d];
}

// ---------------- combine partials + global max per pair
__global__ __launch_bounds__(256) void k_corr_combine(const float* __restrict__ cpart,
                                                      float* __restrict__ corr,
                                                      unsigned* __restrict__ maxb) {
  const size_t PERPAIR = (size_t)2 * 25 * 4096;
  int pair = blockIdx.y;
  size_t i4 = ((size_t)blockIdx.x * 256 + threadIdx.x) * 4;
  f32x4 sacc = {0.f, 0.f, 0.f, 0.f};
#pragma unroll
  for (int p = 0; p < 4; p++)
    sacc += *(const f32x4*)(cpart + ((size_t)(p * 4 + pair)) * PERPAIR + i4);
  *(f32x4*)(corr + (size_t)pair * PERPAIR + i4) = sacc;
  float m = fmaxf(fmaxf(sacc[0], sacc[1]), fmaxf(sacc[2], sacc[3]));
#pragma unroll
  for (int off = 32; off; off >>= 1) m = fmaxf(m, __shfl_xor(m, off));
  __shared__ float wm[4];
  if ((threadIdx.x & 63) == 0) wm[threadIdx.x >> 6] = m;
  __syncthreads();
  if (threadIdx.x == 0) {
    float mm = fmaxf(fmaxf(wm[0], wm[1]), fmaxf(wm[2], wm[3]));
    atomicMax(maxb + pair, encf(mm));
  }
}

// ---------------- softmax + 5x5 gather from bf16 NHWC -> nfpad [pair][b][66][66][512]
// grid (4,4,128): z = b + 2*pair + 8*cgh, cgh in [0,16) -> 4 cg iterations each
__global__ __launch_bounds__(256) void k_attn3(const unsigned short* __restrict__ xf1,
                                               const float* __restrict__ corr,
                                               const unsigned* __restrict__ maxb,
                                               unsigned short* __restrict__ nfpad) {
  __shared__ unsigned short f1t[400 * 8];
  int t = threadIdx.x;
  int tx = t & 15, ty = t >> 4;
  int x0 = blockIdx.x * 16, y0 = blockIdx.y * 16;
  int z = blockIdx.z;
  int b = z & 1, pair = (z >> 1) & 3, cgh = z >> 3;
  const unsigned short* f1 = xf1 + ((size_t)(pair * 2 + b)) * 68 * 68 * 512;
  int y = y0 + ty, x = x0 + tx;
  const float* cr = corr + ((size_t)(pair * 2 + b)) * 25 * 4096 + y * 64 + x;
  float p[25];
  float mx = -1e30f;
#pragma unroll
  for (int d = 0; d < 25; d++) {
    p[d] = cr[(size_t)d * 4096];
    mx = fmaxf(mx, p[d]);
  }
  float gs = 20.f / decf(maxb[pair]);
  float ss = 0.f;
#pragma unroll
  for (int d = 0; d < 25; d++) {
    p[d] = __expf((p[d] - mx) * gs);
    ss += p[d];
  }
  float inv = 1.f / ss;
#pragma unroll
  for (int d = 0; d < 25; d++) p[d] *= inv;

  for (int q = 0; q < 4; ++q) {
    int cg = cgh * 4 + q;
    for (int k = t; k < 400; k += 256) {
      int r = k / 20, c = k - r * 20;
      *(int4v*)&f1t[k * 8] =
          *(const int4v*)&f1[((size_t)(y0 + r) * 68 + (x0 + c)) * 512 + cg * 8];
    }
    __syncthreads();
    float acc[8] = {0.f, 0.f, 0.f, 0.f, 0.f, 0.f, 0.f, 0.f};
#pragma unroll
    for (int d = 0; d < 25; d++) {
      bf16x8 v = *(const bf16x8*)&f1t[((ty + d / 5) * 20 + tx + d % 5) * 8];
      float pd = p[d];
#pragma unroll
      for (int e = 0; e < 8; e++) acc[e] += pd * b2f((unsigned short)v[e]);
    }
    __align__(16) unsigned short o[8];
#pragma unroll
    for (int e = 0; e < 8; e++) o[e] = f2b(acc[e]);
    *(int4v*)&nfpad[(((size_t)(pair * 2 + b) * 66 + (y + 1)) * 66 + (x + 1)) * 512 +
                    cg * 8] = *(const int4v*)o;
    __syncthreads();
  }
}

// ---------------- gate conv (f32 accum, bf16 acts)
__global__ __launch_bounds__(256) void k_gate2(const unsigned short* __restrict__ cp,
                                               const unsigned short* __restrict__ nfp,
                                               const float* __restrict__ wgt,
                                               const float* __restrict__ bg,
                                               float* __restrict__ gw) {
  int t = threadIdx.x;
  int z = blockIdx.z;
  int b = z & 1, pair = z >> 1;
  int y = blockIdx.y;
  int x = blockIdx.x * 8 + (t >> 5);
  int chunk = t & 31;
  int ci0 = chunk * 32;
  int half = ci0 >> 9;
  int ch0 = ci0 & 511;
  const unsigned short* src = half ? (nfp + ((size_t)(pair * 2 + b)) * 66 * 66 * 512)
                                   : (cp + ((size_t)b) * 66 * 66 * 512);
  const float* w = wgt + (size_t)pair * 2 * 9 * 1024;
  float a0 = 0.f, a1 = 0.f, a0b = 0.f, a1b = 0.f;
  for (int tap = 0; tap < 9; ++tap) {
    int ky = tap / 3, kx = tap % 3;
    const unsigned short* ip = src + ((size_t)(y + ky) * 66 + (x + kx)) * 512 + ch0;
    const float* w0 = w + ((size_t)0 * 9 + tap) * 1024 + ci0;
    const float* w1 = w + ((size_t)1 * 9 + tap) * 1024 + ci0;
#pragma unroll
    for (int q = 0; q < 4; ++q) {
      bf16x8 v8 = *(const bf16x8*)(ip + q * 8);
      f32x4 wa = *(const f32x4*)(w0 + q * 8);
      f32x4 wb = *(const f32x4*)(w0 + q * 8 + 4);
      f32x4 wc = *(const f32x4*)(w1 + q * 8);
      f32x4 wd = *(const f32x4*)(w1 + q * 8 + 4);
#pragma unroll
      for (int e = 0; e < 4; e++) {
        float f0 = b2f((unsigned short)v8[e]);
        float f1v = b2f((unsigned short)v8[e + 4]);
        a0 += f0 * wa[e];
        a0b += f1v * wb[e];
        a1 += f0 * wc[e];
        a1b += f1v * wd[e];
      }
    }
  }
  a0 += a0b;
  a1 += a1b;
#pragma unroll
  for (int md = 1; md < 32; md <<= 1) {
    a0 += __shfl_xor(a0, md);
    a1 += __shfl_xor(a1, md);
  }
  if ((t & 31) == 0) {
    float g0 = 1.f / (1.f + __expf(-(a0 + bg[pair * 2 + 0])));
    float g1 = 1.f / (1.f + __expf(-(a1 + bg[pair * 2 + 1])));
    gw[(((size_t)(pair * 2 + b) * 2 + 0) * 64 + y) * 64 + x] = g0;
    gw[(((size_t)(pair * 2 + b) * 2 + 1) * 64 + y) * 64 + x] = g1;
  }
}

// ---------------- fg = [center*g0, nf*g1] -> fgp[pz][2][66][66][1024] bf16
__global__ __launch_bounds__(256) void k_fg(const unsigned short* __restrict__ cp,
                                            const unsigned short* __restrict__ nfp,
                                            const float* __restrict__ gw,
                                            unsigned short* __restrict__ fgp, int pairBase) {
  int pz = blockIdx.y;
  int pair = pairBase + pz;
  unsigned short* dstBase = fgp + (size_t)pz * 2 * 66 * 66 * 1024;
  size_t idx = (size_t)blockIdx.x * 256 + threadIdx.x;
  int chunk = (int)(idx & 127);
  size_t px = idx >> 7;
  int b = (int)(px >> 12), rem = (int)(px & 4095);
  int y = rem >> 6, x = rem & 63;
  int ci0 = chunk * 8;
  int half = ci0 >> 9;
  float g = gw[(((size_t)(pair * 2 + b) * 2 + half) * 64 + y) * 64 + x];
  const unsigned short* src = half ? (nfp + ((size_t)(pair * 2 + b)) * 66 * 66 * 512)
                                   : (cp + (size_t)b * 66 * 66 * 512);
  size_t poff = ((size_t)(y + 1) * 66 + (x + 1)) * 512 + (ci0 - half * 512);
  bf16x8 v = *(const bf16x8*)(src + poff);
  __align__(16) unsigned short o[8];
#pragma unroll
  for (int e = 0; e < 8; e++) o[e] = f2b(b2f((unsigned short)v[e]) * g);
  *(int4v*)(dstBase + ((size_t)(b * 66 + y + 1) * 66 + (x + 1)) * 1024 + ci0) =
      *(const int4v*)o;
}

// ---------------- 256x256x64 implicit-GEMM conv, single barrier per K-tile
// 512 thr, 8 waves (2Mx4N), wave tile 128x64. Quads Q00->Q01->Q11->Q10 with
// fragment register double-buffering; ds_reads/gloads overlap MFMA; compiler
// emits counted lgkmcnt. XCD-aware block decode: bid&7 pins (z,m) per XCD.
// MODE 0: Wd, bf16 out to gatedpad (+bias+relu). MODE 2: Wc split-K/4, bf16 partials.
template <int CI, int MODE>
__global__ __launch_bounds__(512) void conv256(const unsigned short* __restrict__ inB,
                                               const unsigned short* __restrict__ WTb,
                                               const float* __restrict__ bias,
                                               unsigned short* __restrict__ outB,
                                               unsigned short* __restrict__ outP,
                                               int pairOfs, int multiz) {
  constexpr int K = 9 * CI;
  constexpr int KTOT = K / 64;
  constexpr int KT = (MODE == 2) ? KTOT / 4 : KTOT;
  __shared__ unsigned short As[2][256 * 64];
  __shared__ unsigned short Bs[2][256 * 64];

  int t = threadIdx.x;
  int bid = blockIdx.x;
  int xcd = bid & 7, idx = bid >> 3;
  int z, m, n;
  if (multiz) {
    z = xcd >> 1; m = xcd & 1; n = idx;              // 256 blocks
  } else {
    z = 0; m = xcd & 1; n = (xcd >> 1) * 8 + idx;    // 64 blocks
  }
  const unsigned short* inPad = (MODE == 0) ? inB + (size_t)z * 2 * 66 * 66 * 1024 : inB;
  const unsigned short* WT = (MODE == 0) ? WTb + (size_t)z * 512 * 9216 : WTb;
  const int kt0 = (MODE == 2) ? z * KT : 0;
  const int ktEnd = kt0 + KT;
  int co0 = m * 256, n0 = n * 256;

  int aoff[2][2], boff[2][2];
#pragma unroll
  for (int rr = 0; rr < 2; rr++) {
    int idx2 = rr * 512 + t;
    int lr = idx2 >> 3;
    int cg = (idx2 & 7) ^ (lr & 7);
#pragma unroll
    for (int h = 0; h < 2; h++) {
      int row = h * 128 + lr;
      aoff[h][rr] = (co0 + row) * K + cg * 8;
      int ng = n0 + row;
      int bb = ng >> 12, yy = (ng >> 6) & 63, xx = ng & 63;
      boff[h][rr] = ((bb * 66 + yy) * 66 + xx) * CI + cg * 8;
    }
  }

  f32x4 acc[8][4];
#pragma unroll
  for (int i = 0; i < 8; i++)
#pragma unroll
    for (int j = 0; j < 4; j++) acc[i][j] = f32x4{0.f, 0.f, 0.f, 0.f};

  int wid = t >> 6, l = t & 63;
  int wm = wid >> 2, wn = wid & 3;
  int lrow = l & 15, lk4 = l >> 4;

  auto STAGE_A = [&](int buf, int kt) {
#pragma unroll
    for (int h = 0; h < 2; h++)
#pragma unroll
      for (int rr = 0; rr < 2; rr++)
        gload16(WT + (size_t)aoff[h][rr] + kt * 64,
                &As[buf][h * 8192 + (rr * 512 + t) * 8]);
  };
  auto STAGE_B = [&](int buf, int kt) {
    int tap = (CI == 1024) ? (kt >> 4) : (kt >> 5);
    int kci = (CI == 1024) ? ((kt & 15) << 6) : ((kt & 31) << 6);
    int ky = tap / 3, kx = tap - ky * 3;
    int toff = (ky * 66 + kx) * CI + kci;
#pragma unroll
    for (int h = 0; h < 2; h++)
#pragma unroll
      for (int rr = 0; rr < 2; rr++)
        gload16(inPad + (size_t)boff[h][rr] + toff,
                &Bs[buf][h * 8192 + (rr * 512 + t) * 8]);
  };

#define RD_A(BUF, MH, DST)                                                     \
  _Pragma("unroll") for (int ii = 0; ii < 4; ++ii) {                           \
    int row = wm * 128 + (MH)*64 + ii * 16 + lrow;                             \
    _Pragma("unroll") for (int kk = 0; kk < 2; ++kk) {                         \
      int c8 = (kk * 4 + lk4) ^ (lrow & 7);                                    \
      DST[ii][kk] = *(const bf16x8*)&As[BUF][row * 64 + c8 * 8];               \
    }                                                                          \
  }
#define RD_B(BUF, NH, DST)                                                     \
  _Pragma("unroll") for (int j = 0; j < 2; ++j) {                              \
    int row = wn * 64 + (NH)*32 + j * 16 + lrow;                               \
    _Pragma("unroll") for (int kk = 0; kk < 2; ++kk) {                         \
      int c8 = (kk * 4 + lk4) ^ (lrow & 7);                                    \
      DST[j][kk] = *(const bf16x8*)&Bs[BUF][row * 64 + c8 * 8];                \
    }                                                                          \
  }
#define QUAD(AF, BF, MH, NH)                                                   \
  __builtin_amdgcn_s_setprio(1);                                               \
  _Pragma("unroll") for (int ii = 0; ii < 4; ++ii) {                           \
    _Pragma("unroll") for (int j = 0; j < 2; ++j) {                            \
      _Pragma("unroll") for (int kk = 0; kk < 2; ++kk) {                       \
        acc[(MH)*4 + ii][(NH)*2 + j] = __builtin_amdgcn_mfma_f32_16x16x32_bf16(\
            AF[ii][kk], BF[j][kk], acc[(MH)*4 + ii][(NH)*2 + j], 0, 0, 0);     \
      }                                                                        \
    }                                                                          \
  }                                                                            \
  __builtin_amdgcn_s_setprio(0);

  // prologue: stage K-tile kt0, drain (syncthreads emits vmcnt(0)), barrier
  {
    int buf = kt0 & 1;
    STAGE_A(buf, kt0);
    STAGE_B(buf, kt0);
    __syncthreads();
  }

  for (int kt = kt0; kt < ktEnd; ++kt) {
    int cur = kt & 1, nxt = cur ^ 1;
    const bool pf = (kt + 1 < ktEnd);
    bf16x8 afA[4][2], afB[4][2], bfA[2][2], bfB[2][2];
    RD_A(cur, 0, afA);
    RD_B(cur, 0, bfA);
    if (pf) STAGE_A(nxt, kt + 1);
    RD_B(cur, 1, bfB);
    __builtin_amdgcn_sched_barrier(0);
    QUAD(afA, bfA, 0, 0)
    __builtin_amdgcn_sched_barrier(0);
    if (pf) STAGE_B(nxt, kt + 1);
    RD_A(cur, 1, afB);
    __builtin_amdgcn_sched_barrier(0);
    QUAD(afA, bfB, 0, 1)
    __builtin_amdgcn_sched_barrier(0);
    QUAD(afB, bfB, 1, 1)
    QUAD(afB, bfA, 1, 0)
    __syncthreads();  // vmcnt(0)+lgkmcnt(0)+barrier: nxt buffer ready for all
  }
#undef RD_A
#undef RD_B
#undef QUAD

#pragma unroll
  for (int i = 0; i < 8; i++) {
#pragma unroll
    for (int j = 0; j < 4; j++) {
      int col = wn * 64 + j * 16 + lrow;
      int ng = n0 + col;
      int bb = ng >> 12, yy = (ng >> 6) & 63, xx = ng & 63;
#pragma unroll
      for (int r = 0; r < 4; r++) {
        int row = wm * 128 + i * 16 + lk4 * 4 + r;
        int co = co0 + row;
        if (MODE == 0) {
          int zc = (z + pairOfs) * 512 + co;
          float v = acc[i][j][r] + bias[zc];
          v = v > 0.f ? v : 0.f;
          outB[((size_t)(bb * 66 + yy + 1) * 66 + (xx + 1)) * 2048 + zc] = f2b(v);
        } else {
          outP[((size_t)(z * 512 + co) << 13) + ng] = f2b(acc[i][j][r]);
        }
      }
    }
  }
}

// ---------------- combine split-K bf16 partials: out = relu(sum + bias), f32 NCHW
__global__ __launch_bounds__(256) void k_combine2(const unsigned short* __restrict__ p,
                                                  const float* __restrict__ bc,
                                                  float* __restrict__ out) {
  size_t i8 = ((size_t)blockIdx.x * 256 + threadIdx.x) * 8;  // over 512*8192
  int co = (int)(i8 >> 13);
  int ng = (int)(i8 & 8191);
  float s[8] = {0.f, 0.f, 0.f, 0.f, 0.f, 0.f, 0.f, 0.f};
#pragma unroll
  for (int zz = 0; zz < 4; zz++) {
    bf16x8 v = *(const bf16x8*)&p[((size_t)(zz * 512 + co) << 13) + ng];
#pragma unroll
    for (int e = 0; e < 8; e++) s[e] += b2f((unsigned short)v[e]);
  }
  float bb = bc[co];
  int batch = ng >> 12, rem = ng & 4095;
  float* o = out + (((size_t)(batch * 512 + co)) << 12) + rem;
#pragma unroll
  for (int e = 0; e < 8; e++) {
    float q = s[e] + bb;
    o[e] = q > 0.f ? q : 0.f;
  }
}

extern "C" void kernel_launch(void* const* d_in, const int* in_sizes, int n_in,
                              void* d_out, int out_size, void* d_ws, size_t ws_size,
                              hipStream_t stream) {
  const float* x = (const float*)d_in[0];
  const float* Wg = (const float*)d_in[1];
  const float* bg = (const float*)d_in[2];
  const float* Wd = (const float*)d_in[3];
  const float* bd = (const float*)d_in[4];
  const float* Wc = (const float*)d_in[5];
  const float* bc = (const float*)d_in[6];
  float* out = (float*)d_out;

  char* ws = (char*)d_ws;
  size_t off = 0;
  auto alloc = [&](size_t bytes) {
    void* p = ws + off;
    off = (off + bytes + 255) & ~(size_t)255;
    return p;
  };
  const size_t SZ_WDT = (size_t)2048 * 9216 * 2;
  const size_t SZ_WCT = (size_t)512 * 18432 * 2;
  const size_t SZ_WGT = (size_t)4 * 2 * 9 * 1024 * 4;
  const size_t SZ_CP = (size_t)2 * 66 * 66 * 512 * 2;
  const size_t SZ_NF = (size_t)4 * 2 * 66 * 66 * 512 * 2;
  const size_t SZ_GT = (size_t)2 * 66 * 66 * 2048 * 2;
  const size_t SZ_GW = (size_t)4 * 2 * 2 * 4096 * 4;
  const size_t SZ_XF1 = (size_t)4 * 2 * 68 * 68 * 512 * 2;
  const size_t SZ_CORR = (size_t)4 * 2 * 25 * 4096 * 4;
  const size_t SZ_FG1 = (size_t)2 * 66 * 66 * 1024 * 2;
  const size_t SZ_FG4 = SZ_FG1 * 4;

  unsigned short* WdT = (unsigned short*)alloc(SZ_WDT);
  unsigned short* WcT = (unsigned short*)alloc(SZ_WCT);
  float* WgT = (float*)alloc(SZ_WGT);
  unsigned short* centerpad = (unsigned short*)alloc(SZ_CP);
  unsigned short* nfpad = (unsigned short*)alloc(SZ_NF);
  unsigned short* gatedpad = (unsigned short*)alloc(SZ_GT);
  float* gw = (float*)alloc(SZ_GW);
  unsigned* maxb = (unsigned*)alloc(256);

  // union region: phase1 {xf1, corr, cpart} -> phase2 {fg} -> phase3 {wcp}
  size_t unionOff = off;
  unsigned short* xf1 = (unsigned short*)(ws + unionOff);
  size_t o2 = unionOff + ((SZ_XF1 + 255) & ~(size_t)255);
  float* corr = (float*)(ws + o2);
  float* cpart = (float*)(ws + o2 + ((SZ_CORR + 255) & ~(size_t)255));
  unsigned short* fg = (unsigned short*)(ws + unionOff);
  unsigned short* wcp = (unsigned short*)(ws + unionOff);
  bool batched = ws_size >= unionOff + SZ_FG4;
  size_t fgBytes = batched ? SZ_FG4 : SZ_FG1;

  hipMemsetAsync(centerpad, 0, SZ_CP, stream);
  hipMemsetAsync(nfpad, 0, SZ_NF, stream);
  hipMemsetAsync(gatedpad, 0, SZ_GT, stream);
  hipMemsetAsync(maxb, 0, 64, stream);
  hipMemsetAsync(xf1, 0, SZ_XF1, stream);

  k_reorder_w2<<<2048, 256, 0, stream>>>(Wd, WdT, 1024);
  k_reorder_w2<<<512, 256, 0, stream>>>(Wc, WcT, 2048);
  k_reorder_wg<<<288, 256, 0, stream>>>(Wg, WgT);
  k_pad<<<dim3(64, 10), 256, 0, stream>>>(x, xf1, centerpad);
  k_corr<<<dim3(4, 4, 32), 256, 0, stream>>>(x, cpart);
  k_corr_combine<<<dim3(200, 4), 256, 0, stream>>>(cpart, corr, maxb);
  k_attn3<<<dim3(4, 4, 128), 256, 0, stream>>>(xf1, corr, maxb, nfpad);
  k_gate2<<<dim3(8, 64, 8), 256, 0, stream>>>(centerpad, nfpad, WgT, bg, gw);

  // xf1/corr/cpart dead now; reuse union region for fg
  hipMemsetAsync(fg, 0, fgBytes, stream);

  if (batched) {
    k_fg<<<dim3(4096, 4), 256, 0, stream>>>(centerpad, nfpad, gw, fg, 0);
    conv256<1024, 0><<<256, 512, 0, stream>>>(fg, WdT, bd, gatedpad, nullptr, 0, 1);
  } else {
    for (int pair = 0; pair < 4; ++pair) {
      k_fg<<<dim3(4096, 1), 256, 0, stream>>>(centerpad, nfpad, gw, fg, pair);
      conv256<1024, 0><<<64, 512, 0, stream>>>(
          fg, WdT + (size_t)pair * 512 * 9216, bd, gatedpad, nullptr, pair, 0);
    }
  }
  conv256<2048, 2><<<256, 512, 0, stream>>>(gatedpad, WcT, nullptr, nullptr, wcp, 0, 1);
  k_combine2<<<2048, 256, 0, stream>>>(wcp, bc, out);
}